// Round 8
// baseline (1455.318 us; speedup 1.0000x reference)
//
#include <hip/hip_runtime.h>

#define BB 4
#define NPT 16384
#define CIN 128
#define SS 1024
#define NS 32
#define PP 131072   // BB*SS*NS
#define TOPKK 2048

typedef unsigned short u16;
typedef unsigned int u32;
typedef unsigned long long u64;
typedef float v2 __attribute__((ext_vector_type(2)));

// ---------- helpers ----------
__device__ __forceinline__ float bf2f(u32 v){ return __uint_as_float(v << 16); }
__device__ __forceinline__ u16 f2bf(float f){
  u32 u = __float_as_uint(f);
  u32 r = (u + 0x7FFFu + ((u >> 16) & 1u)) >> 16;   // RNE
  return (u16)r;
}
__device__ __forceinline__ u32 keyOf(float m){
  u32 u = __float_as_uint(m);
  return (u & 0x80000000u) ? ~u : (u | 0x80000000u);  // monotone in float order
}

// wave64 u64-max reduction via DPP (VALU pipe, no LDS). Result valid in lane 63.
// bound_ctrl=1: OOB lanes read 0, which always loses (keys are nonzero).
__device__ __forceinline__ u64 wave_max_u64(u64 key){
  #define DPP_STEP(CTRL) { \
    u32 lo_ = (u32)__builtin_amdgcn_update_dpp(0, (int)(u32)key, CTRL, 0xf, 0xf, true); \
    u32 hi_ = (u32)__builtin_amdgcn_update_dpp(0, (int)(u32)(key >> 32), CTRL, 0xf, 0xf, true); \
    u64 ok_ = ((u64)hi_ << 32) | lo_; if (ok_ > key) key = ok_; }
  DPP_STEP(0x111)  // row_shr:1
  DPP_STEP(0x112)  // row_shr:2
  DPP_STEP(0x114)  // row_shr:4
  DPP_STEP(0x118)  // row_shr:8  -> lane15/31/47/63 hold row maxes
  DPP_STEP(0x142)  // row_bcast:15
  DPP_STEP(0x143)  // row_bcast:31 -> lane63 holds wave max
  #undef DPP_STEP
  return key;
}

// ---------- ws layout (bytes) — total 78,748,160 (75.1 MB) ----------
#define OFF_NEWXYZ 0ull                 // B*S*3 f32        49152
#define OFF_MARGIN 49152ull             // B*N f32          262144
#define OFF_FGMASK 311296ull            // B*N u32          262144
#define OFF_IDXNB  573440ull            // B*S*NS i32       524288
#define OFF_MSTAT  1097728ull           // 64*2 f32         512
#define OFF_SSA    1098240ull           // 3*256 float2     6144
#define OFF_WT0    1104384ull           // 128*64 f32       32768
#define OFF_WT1    1137152ull           // 160*128 f32      81920
#define OFF_WT2    1219072ull           // 128*128 f32      65536
#define OFF_WT3    1284608ull           // 128*256 f32      131072
#define OFF_MPART  1415680ull           // 64*1024*2 f64    1048576
#define OFF_CPART  2464256ull           // 256*2048*2 f64   8388608
#define OFF_REGB   10852864ull          // y0 (16MB f32) then Y1 (32MB bf16); cx/cy/cz/cg overlap y0 after k_scores
#define OFF_REGA   44407296ull          // Xb (34.3MB bf16) then Y2 (32MB bf16)
#define WS_NEED    78748160ull

// ---------- prep: transposed/padded fp32 weights ----------
__global__ void k_prep(const float* __restrict__ w1, const float* __restrict__ w2,
                       const float* __restrict__ w3, const float* __restrict__ fw1,
                       float* __restrict__ wt0, float* __restrict__ wt1,
                       float* __restrict__ wt2, float* __restrict__ wt3){
  int gt = blockIdx.x*blockDim.x + threadIdx.x;
  int gs = gridDim.x*blockDim.x;
  for (int i = gt; i < 128*64;  i += gs){ int k=i>>6, m=i&63;  wt0[i] = fw1[m*128+k]; }
  for (int i = gt; i < 160*128; i += gs){ int k=i>>7, m=i&127; wt1[i] = (k<131)? w1[m*131+k] : 0.f; }
  for (int i = gt; i < 128*128; i += gs){ int k=i>>7, m=i&127; wt2[i] = w2[m*128+k]; }
  for (int i = gt; i < 128*256; i += gs){ int k=i>>8, m=i&255; wt3[i] = w3[m*128+k]; }
}

// ---------- mask-head GEMM: y0[b][64][N] = fw1 @ features, + deterministic stat partials ----------
__global__ __launch_bounds__(256) void k_gemm_mask(const float* __restrict__ Wt,    // [128][64]
                                                   const float* __restrict__ feat,  // [B][128][N] f32
                                                   float* __restrict__ y0,
                                                   double* __restrict__ mpart){     // [64][1024][2]
  __shared__ float As[32][64];
  __shared__ float Bs[32][64];
  int t = threadIdx.x, tx = t & 15, ty = t >> 4;
  int p0 = blockIdx.x * 64; int b = blockIdx.z;
  const float* X = feat + (size_t)b * CIN * NPT;
  float acc[4][4] = {};
  int e = t * 8, ka = e >> 6, ca = e & 63;
  for (int kc = 0; kc < 4; kc++){
    const float* wr = Wt + (size_t)(kc*32 + ka) * 64 + ca;
    float4 w0 = *(const float4*)wr;
    float4 w1v = *(const float4*)(wr + 4);
    const float* br = X + (size_t)(kc*32 + ka) * NPT + p0 + ca;
    float4 b0 = *(const float4*)br;
    float4 b1 = *(const float4*)(br + 4);
    __syncthreads();
    *(float4*)&As[ka][ca] = w0; *(float4*)&As[ka][ca+4] = w1v;
    *(float4*)&Bs[ka][ca] = b0; *(float4*)&Bs[ka][ca+4] = b1;
    __syncthreads();
    #pragma unroll
    for (int k = 0; k < 32; k++){
      float4 a = *(float4*)&As[k][ty*4];
      float4 bq = *(float4*)&Bs[k][tx*4];
      float av[4] = {a.x,a.y,a.z,a.w}; float bw[4] = {bq.x,bq.y,bq.z,bq.w};
      #pragma unroll
      for (int i = 0; i < 4; i++)
        #pragma unroll
        for (int j = 0; j < 4; j++) acc[i][j] = fmaf(av[i], bw[j], acc[i][j]);
    }
  }
  #pragma unroll
  for (int i = 0; i < 4; i++){
    int m = ty*4 + i;
    float4 v = make_float4(acc[i][0], acc[i][1], acc[i][2], acc[i][3]);
    *(float4*)(y0 + ((size_t)(b*64 + m)) * NPT + p0 + tx*4) = v;
  }
  __syncthreads();
  float* red = (float*)As;  // 2048 floats
  #pragma unroll
  for (int i = 0; i < 4; i++){
    float s = 0.f, q = 0.f;
    #pragma unroll
    for (int j = 0; j < 4; j++){ s += acc[i][j]; q += acc[i][j]*acc[i][j]; }
    red[((ty*4+i)*16 + tx)*2] = s; red[((ty*4+i)*16 + tx)*2 + 1] = q;
  }
  __syncthreads();
  if (t < 64){
    double s = 0.0, q = 0.0;
    for (int x = 0; x < 16; x++){ s += red[(t*16+x)*2]; q += red[(t*16+x)*2+1]; }
    int slot = b*256 + blockIdx.x;
    mpart[((size_t)t*1024 + slot)*2] = s;
    mpart[((size_t)t*1024 + slot)*2 + 1] = q;
  }
}

__global__ void k_mask_stats(const double* __restrict__ mpart, float* __restrict__ mstat){ // <<<1,64>>>
  int t = threadIdx.x;
  double s = 0.0, q = 0.0;
  for (int i = 0; i < 1024; i++){ s += mpart[((size_t)t*1024 + i)*2]; q += mpart[((size_t)t*1024 + i)*2+1]; }
  double cnt = 65536.0;
  double mu = s/cnt; double var = q/cnt - mu*mu;
  float muf = (float)mu;
  float rs = 1.0f / sqrtf((float)var + 1e-5f);
  mstat[t*2] = muf; mstat[t*2+1] = rs;
}

// ---------- scores + margin ----------
__global__ __launch_bounds__(256) void k_scores(const float* __restrict__ y0, const float* __restrict__ mstat,
                                                const float* __restrict__ fg1, const float* __restrict__ fb1,
                                                const float* __restrict__ fw2, const float* __restrict__ fbias2,
                                                float* __restrict__ margin, float* __restrict__ out3){
  __shared__ float smu[64], srs[64], sg[64], sb[64], sw[128];
  int t = threadIdx.x; int b = blockIdx.y; int n = blockIdx.x*256 + t;
  if (t < 64){ smu[t] = mstat[t*2]; srs[t] = mstat[t*2+1]; sg[t] = fg1[t]; sb[t] = fb1[t]; }
  if (t < 128) sw[t] = fw2[t];
  __syncthreads();
  float a0 = 0.f, a1 = 0.f;
  const float* yb = y0 + (size_t)b*64*NPT + n;
  for (int o = 0; o < 64; o++){
    float y = yb[(size_t)o * NPT];
    float h = __fmul_rn(__fmul_rn(__fsub_rn(y, smu[o]), srs[o]), sg[o]);
    h = __fadd_rn(h, sb[o]);
    h = fmaxf(h, 0.f);
    a0 = fmaf(sw[o], h, a0);
    a1 = fmaf(sw[64+o], h, a1);
  }
  float s0 = __fadd_rn(a0, fbias2[0]);
  float s1 = __fadd_rn(a1, fbias2[1]);
  out3[(size_t)(b*2)*NPT + n] = s0;
  out3[(size_t)(b*2+1)*NPT + n] = s1;
  float m = fmaxf(s0, s1);
  float e0 = expf(__fsub_rn(s0, m));
  float e1 = expf(__fsub_rn(s1, m));
  float den = __fadd_rn(e0, e1);
  float mg = __fsub_rn(__fdiv_rn(e1, den), __fdiv_rn(e0, den));
  margin[b*NPT + n] = mg;
}

// ---------- top-2048 per batch -> fg mask (radix select + ballot-scan flag phase) ----------
__global__ __launch_bounds__(1024) void k_topk(const float* __restrict__ margin, u32* __restrict__ fgmask){
  int t = threadIdx.x; int b = blockIdx.x;
  int lane = t & 63, wv = t >> 6;
  const float* mg = margin + b*NPT; u32* fm = fgmask + b*NPT;
  __shared__ int hist[256];
  __shared__ int swt[2][16];
  __shared__ u32 s_bin; __shared__ int s_need;
  int need = TOPKK; u32 prefix = 0, kmask = 0;
  for (int r = 0; r < 4; r++){
    int shift = 24 - 8*r;
    if (t < 256) hist[t] = 0;
    __syncthreads();
    for (int j = 0; j < 16; j++){
      u32 key = keyOf(mg[j*1024 + t]);
      if ((key & kmask) == prefix) atomicAdd(&hist[(key >> shift) & 255], 1);
    }
    __syncthreads();
    if (t == 0){
      int cum = 0;
      for (int bin = 255; bin >= 0; bin--){
        int c = hist[bin];
        if (cum + c >= need){ s_bin = (u32)bin; s_need = need - cum; break; }
        cum += c;
      }
    }
    __syncthreads();
    prefix |= s_bin << shift; kmask |= 255u << shift; need = s_need;
    __syncthreads();
  }
  u32 T = prefix;
  int run = 0;   // thread-local replica of the running count (all threads identical)
  for (int j = 0; j < 16; j++){
    int n = j*1024 + t;
    u32 key = keyOf(mg[n]);
    int eq = (key == T) ? 1 : 0;
    int gt = (key > T) ? 1 : 0;
    u64 bal = __ballot(eq != 0);
    int lexcl = __popcll(bal & ((1ull << lane) - 1ull));
    if (lane == 0) swt[j & 1][wv] = __popcll(bal);
    __syncthreads();
    int base = 0, tot = 0;
    #pragma unroll
    for (int w = 0; w < 16; w++){
      int c = swt[j & 1][w];
      tot += c;
      if (w < wv) base += c;
    }
    int excl = base + lexcl;
    int flag = gt | (eq & ((run + excl) < need ? 1 : 0));
    fm[n] = (u32)flag;
    run += tot;
  }
}

// ---------- compact masked candidates (stable, ascending index) ----------
// 8 blocks: (b, which). fg -> 2048 entries at seg base b*16384; bg -> 14336 at +2048.
__global__ __launch_bounds__(1024) void k_compact(const float* __restrict__ xyz, const u32* __restrict__ fgmask,
                                                  float* __restrict__ cx, float* __restrict__ cy,
                                                  float* __restrict__ cz, int* __restrict__ cg){
  int blk = blockIdx.x; int b = blk >> 1; int which = blk & 1;
  const float* xb = xyz + (size_t)b * NPT * 3;
  const u32* mb = fgmask + b*NPT;
  int t = threadIdx.x;
  __shared__ int sc[1024];
  u32 mloc = 0; int cnt = 0;
  int p0 = t*16;
  #pragma unroll
  for (int j = 0; j < 16; j++){
    u32 m = mb[p0+j];
    bool inc = which ? (m == 0u) : (m != 0u);
    mloc |= (inc ? 1u : 0u) << j; cnt += inc ? 1 : 0;
  }
  sc[t] = cnt; __syncthreads();
  for (int off = 1; off < 1024; off <<= 1){
    int v = (t >= off) ? sc[t-off] : 0;
    __syncthreads();
    sc[t] += v;
    __syncthreads();
  }
  int pos = sc[t] - cnt;
  int base = b*16384 + (which ? 2048 : 0);
  for (int j = 0; j < 16; j++){
    if ((mloc >> j) & 1u){
      int p = p0 + j;
      cx[base+pos] = xb[p*3]; cy[base+pos] = xb[p*3+1]; cz[base+pos] = xb[p*3+2];
      cg[base+pos] = p; pos++;
    }
  }
}

// ---------- masked FPS on compacted candidates ----------
// Wave reduce via DPP (lane 63 -> plain ds_write, no atomics, no bank conflicts).
// Key = keyOf(v)<<14 | (16383-idx): exact lowest-index tie-break (compaction
// preserves ascending order). All 8 slots rewritten every iteration; parity
// double-buffer + single barrier.
template<int NV>   // v2-rows per thread; candidates = NV*1024 (512 threads)
__device__ __forceinline__ void fps_run(const float* __restrict__ cx, const float* __restrict__ cy,
                                        const float* __restrict__ cz, const int* __restrict__ cg,
                                        int b, int which,
                                        float* __restrict__ newxyz, float* __restrict__ out0,
                                        float* __restrict__ out2){
  #pragma clang fp contract(off)
  int t = threadIdx.x;
  int wv = t >> 6;
  __shared__ u64 sw[2][8];
  v2 px[NV], py[NV], pz[NV], mind[NV];
  #pragma unroll
  for (int r = 0; r < NV; r++){
    int p0 = 1024*r + t, p1 = 1024*r + 512 + t;
    px[r].x = cx[p0]; px[r].y = cx[p1];
    py[r].x = cy[p0]; py[r].y = cy[p1];
    pz[r].x = cz[p0]; pz[r].y = cz[p1];
    mind[r].x = 1e10f; mind[r].y = 1e10f;
  }
  float bv = 1e10f; int bi = t;   // all equal -> lowest local index
  for (int it = 0; it < 512; it++){
    u64 key = ((u64)keyOf(bv) << 14) | (u64)(16383 - bi);
    key = wave_max_u64(key);
    if ((t & 63) == 63) sw[it & 1][wv] = key;
    __syncthreads();
    u64 k0 = sw[it & 1][0];
    #pragma unroll
    for (int i = 1; i < 8; i++){ u64 ki = sw[it & 1][i]; if (ki > k0) k0 = ki; }
    int sel = 16383 - (int)(k0 & 0x3FFFu);
    float xs = cx[sel], ys = cy[sel], zs = cz[sel];   // uniform L2-resident load
    if (t == 0){
      int s = which*512 + it;
      out2[b*1024 + s] = (float)cg[sel];
      newxyz[(b*1024 + s)*3]   = xs;
      newxyz[(b*1024 + s)*3+1] = ys;
      newxyz[(b*1024 + s)*3+2] = zs;
      out0[(b*1024 + s)*3]   = xs;
      out0[(b*1024 + s)*3+1] = ys;
      out0[(b*1024 + s)*3+2] = zs;
    }
    v2 xs2; xs2.x = xs; xs2.y = xs;
    v2 ys2; ys2.x = ys; ys2.y = ys;
    v2 zs2; zs2.x = zs; zs2.y = zs;
    bv = -1.0f; bi = 16383;
    #pragma unroll
    for (int r = 0; r < NV; r++){
      v2 dx = px[r] - xs2;
      v2 dy = py[r] - ys2;
      v2 dz = pz[r] - zs2;
      v2 qx = dx * dx;
      v2 qy = dy * dy;
      v2 qz = dz * dz;
      v2 s1 = qx + qy;
      v2 d  = s1 + qz;
      float m0 = fminf(mind[r].x, d.x);
      float m1 = fminf(mind[r].y, d.y);
      mind[r].x = m0; mind[r].y = m1;
      if (m0 > bv){ bv = m0; bi = 1024*r + t; }
      if (m1 > bv){ bv = m1; bi = 1024*r + 512 + t; }
    }
  }
}

__global__ __launch_bounds__(512) void k_fps(const float* __restrict__ cx, const float* __restrict__ cy,
                                             const float* __restrict__ cz, const int* __restrict__ cg,
                                             float* __restrict__ newxyz, float* __restrict__ out0,
                                             float* __restrict__ out2){
  int b = blockIdx.x >> 1; int which = blockIdx.x & 1;
  int base = b*16384 + (which ? 2048 : 0);
  if (which) fps_run<14>(cx+base, cy+base, cz+base, cg+base, b, 1, newxyz, out0, out2);
  else       fps_run<2 >(cx+base, cy+base, cz+base, cg+base, b, 0, newxyz, out0, out2);
}

// ---------- ball query: one wave per query (inclusive <=, f32 radius^2) ----------
__global__ __launch_bounds__(256) void k_ball(const float* __restrict__ xyz, const float* __restrict__ newxyz,
                                              int* __restrict__ idxnb){
  int t = threadIdx.x; int lane = t & 63;
  int qid = blockIdx.x*4 + (t >> 6);
  int b = qid >> 10;
  const float* xb = xyz + (size_t)b * NPT * 3;
  float qx = newxyz[qid*3], qy = newxyz[qid*3+1], qz = newxyz[qid*3+2];
  int found = 0, first = -1;
  for (int base = 0; base < NPT; base += 64){
    int p = base + lane;
    float x = xb[p*3], y = xb[p*3+1], z = xb[p*3+2];
    float dx = __fsub_rn(qx, x), dy = __fsub_rn(qy, y), dz = __fsub_rn(qz, z);
    float d2 = __fadd_rn(__fadd_rn(__fmul_rn(dx,dx), __fmul_rn(dy,dy)), __fmul_rn(dz,dz));
    bool w = d2 <= 0.09f;
    u64 m = __ballot(w);
    if (first < 0 && m) first = base + __ffsll((unsigned long long)m) - 1;
    if (w){
      int pos = found + __popcll(m & ((1ull << lane) - 1ull));
      if (pos < NS) idxnb[(size_t)qid*NS + pos] = p;
    }
    found += __popcll(m);
    if (found >= NS) break;
  }
  if (first < 0) first = 0;   // defensive
  if (lane < NS && lane >= found) idxnb[(size_t)qid*NS + lane] = first;
}

// ---------- build grouped input X [131][P] bf16 ----------
__global__ __launch_bounds__(256) void k_buildX(const float* __restrict__ xyz, const float* __restrict__ newxyz,
                                                const int* __restrict__ idxnb, const float* __restrict__ feat,
                                                u16* __restrict__ Xb){
  int pos = blockIdx.x*256 + threadIdx.x;
  int b = pos >> 15; int r = pos & 32767; int s = r >> 5;
  int gi = idxnb[pos] & (NPT - 1);   // defensive clamp
  const float* xp = xyz + ((size_t)b*NPT + gi) * 3;
  const float* qp = newxyz + ((size_t)(b << 10) + s) * 3;
  #pragma unroll
  for (int c = 0; c < 3; c++) Xb[(size_t)c*PP + pos] = f2bf(__fsub_rn(xp[c], qp[c]));
  const float* fb = feat + (size_t)b*CIN*NPT + gi;
  for (int c = 0; c < CIN; c++) Xb[(size_t)(3+c)*PP + pos] = f2bf(fb[(size_t)c * NPT]);
}

// ---------- conv GEMM: Y[M][P] bf16 = Wt^T (fp32) x (affine?relu? X bf16), + stat partials ----------
template<int AFF, int STORE>
__global__ __launch_bounds__(256) void k_gemm_conv(const float* __restrict__ Wt, int Mtot,
                                                   const u16* __restrict__ Xin, int Kvalid, int nkc,
                                                   const float2* __restrict__ aff,
                                                   u16* __restrict__ Yout, double* __restrict__ cpart){
  __shared__ float As[32][64];
  __shared__ float Bs[32][64];
  int t = threadIdx.x, tx = t & 15, ty = t >> 4;
  int p0 = blockIdx.x * 64, m0 = blockIdx.y * 64;
  float acc[4][4] = {};
  int e = t * 8, ka = e >> 6, ca = e & 63;
  for (int kc = 0; kc < nkc; kc++){
    int kg = kc*32 + ka;
    const float* wr = Wt + (size_t)kg * Mtot + m0 + ca;
    float4 w0 = *(const float4*)wr;
    float4 w1v = *(const float4*)(wr + 4);
    float bv[8];
    if (kg < Kvalid){
      uint4 u = *(const uint4*)(Xin + (size_t)kg * PP + p0 + ca);
      u32 us[4] = {u.x, u.y, u.z, u.w};
      #pragma unroll
      for (int q = 0; q < 4; q++){ bv[2*q] = bf2f(us[q] & 0xFFFFu); bv[2*q+1] = bf2f(us[q] >> 16); }
      if (AFF){
        float2 af = aff[kg];
        #pragma unroll
        for (int q = 0; q < 8; q++) bv[q] = fmaxf(0.f, fmaf(bv[q], af.x, af.y));
      }
    } else {
      #pragma unroll
      for (int q = 0; q < 8; q++) bv[q] = 0.f;
    }
    __syncthreads();
    *(float4*)&As[ka][ca] = w0; *(float4*)&As[ka][ca+4] = w1v;
    #pragma unroll
    for (int q = 0; q < 8; q++) Bs[ka][ca+q] = bv[q];
    __syncthreads();
    #pragma unroll
    for (int k = 0; k < 32; k++){
      float4 a = *(float4*)&As[k][ty*4];
      float4 bq = *(float4*)&Bs[k][tx*4];
      float av[4] = {a.x,a.y,a.z,a.w}; float bw[4] = {bq.x,bq.y,bq.z,bq.w};
      #pragma unroll
      for (int i = 0; i < 4; i++)
        #pragma unroll
        for (int j = 0; j < 4; j++) acc[i][j] = fmaf(av[i], bw[j], acc[i][j]);
    }
  }
  if (STORE){
    #pragma unroll
    for (int i = 0; i < 4; i++){
      int m = m0 + ty*4 + i;
      ushort4 pk;
      pk.x = f2bf(acc[i][0]); pk.y = f2bf(acc[i][1]); pk.z = f2bf(acc[i][2]); pk.w = f2bf(acc[i][3]);
      *(ushort4*)(Yout + (size_t)m * PP + p0 + tx*4) = pk;
    }
  }
  __syncthreads();
  float* red = (float*)As;
  #pragma unroll
  for (int i = 0; i < 4; i++){
    float s = 0.f, q = 0.f;
    #pragma unroll
    for (int j = 0; j < 4; j++){ s += acc[i][j]; q += acc[i][j]*acc[i][j]; }
    red[((ty*4+i)*16 + tx)*2] = s; red[((ty*4+i)*16 + tx)*2 + 1] = q;
  }
  __syncthreads();
  if (t < 64){
    double s = 0.0, q = 0.0;
    for (int x = 0; x < 16; x++){ s += red[(t*16+x)*2]; q += red[(t*16+x)*2+1]; }
    cpart[((size_t)(m0 + t)*2048 + blockIdx.x)*2] = s;
    cpart[((size_t)(m0 + t)*2048 + blockIdx.x)*2 + 1] = q;
  }
}

__global__ __launch_bounds__(256) void k_stats_conv(const double* __restrict__ cpart,
                                                    const float* __restrict__ g, const float* __restrict__ bt,
                                                    float2* __restrict__ ssv){
  __shared__ double rs_[256], rq_[256];
  int ch = blockIdx.x, t = threadIdx.x;
  double s = 0.0, q = 0.0;
  for (int i = t; i < 2048; i += 256){ s += cpart[((size_t)ch*2048 + i)*2]; q += cpart[((size_t)ch*2048 + i)*2+1]; }
  rs_[t] = s; rq_[t] = q; __syncthreads();
  for (int off = 128; off; off >>= 1){
    if (t < off){ rs_[t] += rs_[t+off]; rq_[t] += rq_[t+off]; }
    __syncthreads();
  }
  if (t == 0){
    double cnt = (double)PP;
    double mu = rs_[0]/cnt; double var = rq_[0]/cnt - mu*mu;
    float rsf = 1.0f / sqrtf((float)var + 1e-5f);
    double rsd = (double)rsf;
    double gd = (double)g[ch]; double bd = (double)bt[ch];
    ssv[ch] = make_float2((float)(rsd*gd), (float)(bd - mu*rsd*gd));
  }
}

// ---------- fused layer-3 recompute + BN3 + relu + maxpool (one block per query) ----------
__global__ __launch_bounds__(256) void k_fuse3pool(const u16* __restrict__ Y2, const float* __restrict__ wt3,
                                                   const float2* __restrict__ ss1, const float2* __restrict__ ss2,
                                                   float* __restrict__ out1){
  __shared__ float Xs[128][32];
  int t = threadIdx.x;
  int q = blockIdx.x;            // b*1024 + s
  int b = q >> 10, s = q & 1023;
  size_t cb = (size_t)q << 5;    // column base in P
  #pragma unroll
  for (int e = 0; e < 16; e++){
    int idx = e*256 + t; int k = idx >> 5, j = idx & 31;
    float v = bf2f(Y2[(size_t)k*PP + cb + j]);
    float2 af = ss1[k];
    Xs[k][j] = fmaxf(0.f, fmaf(v, af.x, af.y));
  }
  __syncthreads();
  float acc[32] = {};
  for (int k = 0; k < 128; k++){
    float w = wt3[k*256 + t];
    const float4* xr = (const float4*)&Xs[k][0];
    #pragma unroll
    for (int jq = 0; jq < 8; jq++){
      float4 x = xr[jq];
      acc[jq*4+0] = fmaf(w, x.x, acc[jq*4+0]);
      acc[jq*4+1] = fmaf(w, x.y, acc[jq*4+1]);
      acc[jq*4+2] = fmaf(w, x.z, acc[jq*4+2]);
      acc[jq*4+3] = fmaf(w, x.w, acc[jq*4+3]);
    }
  }
  float2 a2 = ss2[t];
  float mx = 0.f;
  #pragma unroll
  for (int j = 0; j < 32; j++) mx = fmaxf(mx, fmaxf(0.f, fmaf(acc[j], a2.x, a2.y)));
  out1[((size_t)b << 18) + (size_t)t*1024 + s] = mx;
}

extern "C" void kernel_launch(void* const* d_in, const int* in_sizes, int n_in,
                              void* d_out, int out_size, void* d_ws, size_t ws_size,
                              hipStream_t stream){
  (void)in_sizes; (void)n_in; (void)out_size;
  if (ws_size < WS_NEED) return;
  const float* xyz    = (const float*)d_in[0];
  const float* feat   = (const float*)d_in[1];
  const float* w1     = (const float*)d_in[2];
  const float* g1     = (const float*)d_in[3];
  const float* b1     = (const float*)d_in[4];
  const float* w2     = (const float*)d_in[5];
  const float* g2     = (const float*)d_in[6];
  const float* b2     = (const float*)d_in[7];
  const float* w3     = (const float*)d_in[8];
  const float* g3     = (const float*)d_in[9];
  const float* b3     = (const float*)d_in[10];
  const float* fw1    = (const float*)d_in[11];
  const float* fg1    = (const float*)d_in[12];
  const float* fb1    = (const float*)d_in[13];
  const float* fw2    = (const float*)d_in[14];
  const float* fbias2 = (const float*)d_in[15];

  char* ws = (char*)d_ws;
  float*  newxyz = (float*)(ws + OFF_NEWXYZ);
  float*  margin = (float*)(ws + OFF_MARGIN);
  u32*    fgmask = (u32*)(ws + OFF_FGMASK);
  int*    idxnb  = (int*)(ws + OFF_IDXNB);
  float*  mstat  = (float*)(ws + OFF_MSTAT);
  float2* ss0    = (float2*)(ws + OFF_SSA);
  float2* ss1    = ss0 + 256;
  float2* ss2    = ss0 + 512;
  float*  wt0    = (float*)(ws + OFF_WT0);
  float*  wt1    = (float*)(ws + OFF_WT1);
  float*  wt2    = (float*)(ws + OFF_WT2);
  float*  wt3    = (float*)(ws + OFF_WT3);
  double* mpart  = (double*)(ws + OFF_MPART);
  double* cpart  = (double*)(ws + OFF_CPART);
  float*  y0     = (float*)(ws + OFF_REGB);   // 16 MB f32, dead after k_scores
  u16*    Y1     = (u16*)(ws + OFF_REGB);     // 32 MB bf16 (written at layer-1, after k_fps done)
  u16*    Xb     = (u16*)(ws + OFF_REGA);     // 34.3 MB bf16, dead after layer-1
  u16*    Y2     = (u16*)(ws + OFF_REGA);     // 32 MB bf16
  // compact candidate arrays overlap dead y0 (written by k_compact after k_scores,
  // read by k_fps, dead before layer-1 writes Y1 in the same region)
  float*  cx     = (float*)(ws + OFF_REGB);
  float*  cy     = cx + 4*16384;
  float*  cz     = cy + 4*16384;
  int*    cg     = (int*)(cz + 4*16384);

  float* out  = (float*)d_out;
  float* out0 = out;            // [4,1024,3]
  float* out1 = out + 12288;    // [4,256,1024]
  float* out2 = out + 1060864;  // [4,1024]
  float* out3 = out + 1064960;  // [4,2,16384]

  k_prep<<<dim3(256), dim3(256), 0, stream>>>(w1, w2, w3, fw1, wt0, wt1, wt2, wt3);
  k_gemm_mask<<<dim3(256,1,4), dim3(256), 0, stream>>>(wt0, feat, y0, mpart);
  k_mask_stats<<<dim3(1), dim3(64), 0, stream>>>(mpart, mstat);
  k_scores<<<dim3(64,4), dim3(256), 0, stream>>>(y0, mstat, fg1, fb1, fw2, fbias2, margin, out3);
  k_topk<<<dim3(4), dim3(1024), 0, stream>>>(margin, fgmask);
  k_compact<<<dim3(8), dim3(1024), 0, stream>>>(xyz, fgmask, cx, cy, cz, cg);
  k_fps<<<dim3(8), dim3(512), 0, stream>>>(cx, cy, cz, cg, newxyz, out0, out2);
  k_ball<<<dim3(1024), dim3(256), 0, stream>>>(xyz, newxyz, idxnb);
  k_buildX<<<dim3(512), dim3(256), 0, stream>>>(xyz, newxyz, idxnb, feat, Xb);
  k_gemm_conv<0,1><<<dim3(2048,2), dim3(256), 0, stream>>>(wt1, 128, Xb, 131, 5, nullptr, Y1, cpart);
  k_stats_conv<<<dim3(128), dim3(256), 0, stream>>>(cpart, g1, b1, ss0);
  k_gemm_conv<1,1><<<dim3(2048,2), dim3(256), 0, stream>>>(wt2, 128, Y1, 128, 4, ss0, Y2, cpart);
  k_stats_conv<<<dim3(128), dim3(256), 0, stream>>>(cpart, g2, b2, ss1);
  k_gemm_conv<1,0><<<dim3(2048,4), dim3(256), 0, stream>>>(wt3, 256, Y2, 128, 4, ss1, nullptr, cpart);
  k_stats_conv<<<dim3(256), dim3(256), 0, stream>>>(cpart, g3, b3, ss2);
  k_fuse3pool<<<dim3(4096), dim3(256), 0, stream>>>(Y2, wt3, ss1, ss2, out1);
}

// Round 9
// 1361.864 us; speedup vs baseline: 1.0686x; 1.0686x over previous
//
#include <hip/hip_runtime.h>

#define BB 4
#define NPT 16384
#define CIN 128
#define SS 1024
#define NS 32
#define PP 131072   // BB*SS*NS
#define TOPKK 2048

typedef unsigned short u16;
typedef unsigned int u32;
typedef unsigned long long u64;
typedef float v2 __attribute__((ext_vector_type(2)));
typedef short bf16x8 __attribute__((ext_vector_type(8)));
typedef float f32x4 __attribute__((ext_vector_type(4)));

// ---------- helpers ----------
__device__ __forceinline__ float bf2f(u32 v){ return __uint_as_float(v << 16); }
__device__ __forceinline__ u16 f2bf(float f){
  u32 u = __float_as_uint(f);
  u32 r = (u + 0x7FFFu + ((u >> 16) & 1u)) >> 16;   // RNE
  return (u16)r;
}
__device__ __forceinline__ u32 keyOf(float m){
  u32 u = __float_as_uint(m);
  return (u & 0x80000000u) ? ~u : (u | 0x80000000u);  // monotone in float order
}

// f32 wave64 max via DPP (cheap 32-bit chain), result broadcast to all lanes.
// bound_ctrl=1 fills 0, which never wins since all inputs are >= 0.
__device__ __forceinline__ float wave_max_f32(float v){
  #define STEP(CTRL) { int o_ = __builtin_amdgcn_update_dpp(0, __float_as_int(v), CTRL, 0xf, 0xf, true); \
                       v = fmaxf(v, __int_as_float(o_)); }
  STEP(0x111) STEP(0x112) STEP(0x114) STEP(0x118)  // row_shr 1,2,4,8
  STEP(0x142) STEP(0x143)                           // row_bcast 15, 31 -> lane63 = wave max
  #undef STEP
  return __int_as_float(__builtin_amdgcn_readlane(__float_as_int(v), 63));
}

// ---------- ws layout (bytes) — total 86,342,144 (82.3 MB) ----------
#define OFF_NEWXYZ 0ull                 // B*S*3 f32        49152
#define OFF_MARGIN 49152ull             // B*N f32          262144
#define OFF_FGMASK 311296ull            // B*N u32          262144
#define OFF_IDXNB  573440ull            // B*S*NS i32       524288
#define OFF_MSTAT  1097728ull           // 64*2 f32         512
#define OFF_SSA    1098240ull           // 512 float2       6144 (ss0:128, ss1:128, ss2:256)
#define OFF_WT0    1104384ull           // 128*64 f32       32768
#define OFF_W1B    1137152ull           // 128*160 bf16     40960
#define OFF_W2B    1178112ull           // 128*128 bf16     32768
#define OFF_W3B    1210880ull           // 256*128 bf16     65536
#define OFF_WT3F   1276416ull           // 128*256 f32      131072
#define OFF_MPART  1407488ull           // 64*1024*2 f64    1048576
#define OFF_CPART  2456064ull           // 256*2048*2 f64   8388608
#define OFF_REGB   10844672ull          // Y1p 32MB bf16 (K8)
#define OFF_REGA   44399104ull          // y0(16MB) -> cxyz(1MB) -> Xb2(40MB K8) -> Y2p(32MB K8)
#define WS_NEED    86342144ull

// ---------- prep: weights (fp32 mask-head; bf16 [M][Kpad] for MFMA; f32 wt3 for fuse3pool) ----------
__global__ void k_prep(const float* __restrict__ w1, const float* __restrict__ w2,
                       const float* __restrict__ w3, const float* __restrict__ fw1,
                       float* __restrict__ wt0, u16* __restrict__ w1b, u16* __restrict__ w2b,
                       u16* __restrict__ w3b, float* __restrict__ wt3f){
  int gt = blockIdx.x*blockDim.x + threadIdx.x;
  int gs = gridDim.x*blockDim.x;
  for (int i = gt; i < 128*64;  i += gs){ int k=i>>6, m=i&63;  wt0[i] = fw1[m*128+k]; }
  for (int i = gt; i < 128*160; i += gs){ int m=i/160, k=i-m*160; w1b[i] = (k<131)? f2bf(w1[m*131+k]) : (u16)0; }
  for (int i = gt; i < 128*128; i += gs){ w2b[i] = f2bf(w2[i]); }
  for (int i = gt; i < 256*128; i += gs){ w3b[i] = f2bf(w3[i]); }
  for (int i = gt; i < 128*256; i += gs){ int k=i>>8, m=i&255; wt3f[i] = w3[m*128+k]; }
}

// ---------- mask-head GEMM (fp32 exact path): y0[b][64][N] + deterministic stat partials ----------
__global__ __launch_bounds__(256) void k_gemm_mask(const float* __restrict__ Wt,    // [128][64]
                                                   const float* __restrict__ feat,  // [B][128][N] f32
                                                   float* __restrict__ y0,
                                                   double* __restrict__ mpart){     // [64][1024][2]
  __shared__ float As[32][64];
  __shared__ float Bs[32][64];
  int t = threadIdx.x, tx = t & 15, ty = t >> 4;
  int p0 = blockIdx.x * 64; int b = blockIdx.z;
  const float* X = feat + (size_t)b * CIN * NPT;
  float acc[4][4] = {};
  int e = t * 8, ka = e >> 6, ca = e & 63;
  for (int kc = 0; kc < 4; kc++){
    const float* wr = Wt + (size_t)(kc*32 + ka) * 64 + ca;
    float4 w0 = *(const float4*)wr;
    float4 w1v = *(const float4*)(wr + 4);
    const float* br = X + (size_t)(kc*32 + ka) * NPT + p0 + ca;
    float4 b0 = *(const float4*)br;
    float4 b1 = *(const float4*)(br + 4);
    __syncthreads();
    *(float4*)&As[ka][ca] = w0; *(float4*)&As[ka][ca+4] = w1v;
    *(float4*)&Bs[ka][ca] = b0; *(float4*)&Bs[ka][ca+4] = b1;
    __syncthreads();
    #pragma unroll
    for (int k = 0; k < 32; k++){
      float4 a = *(float4*)&As[k][ty*4];
      float4 bq = *(float4*)&Bs[k][tx*4];
      float av[4] = {a.x,a.y,a.z,a.w}; float bw[4] = {bq.x,bq.y,bq.z,bq.w};
      #pragma unroll
      for (int i = 0; i < 4; i++)
        #pragma unroll
        for (int j = 0; j < 4; j++) acc[i][j] = fmaf(av[i], bw[j], acc[i][j]);
    }
  }
  #pragma unroll
  for (int i = 0; i < 4; i++){
    int m = ty*4 + i;
    float4 v = make_float4(acc[i][0], acc[i][1], acc[i][2], acc[i][3]);
    *(float4*)(y0 + ((size_t)(b*64 + m)) * NPT + p0 + tx*4) = v;
  }
  __syncthreads();
  float* red = (float*)As;
  #pragma unroll
  for (int i = 0; i < 4; i++){
    float s = 0.f, q = 0.f;
    #pragma unroll
    for (int j = 0; j < 4; j++){ s += acc[i][j]; q += acc[i][j]*acc[i][j]; }
    red[((ty*4+i)*16 + tx)*2] = s; red[((ty*4+i)*16 + tx)*2 + 1] = q;
  }
  __syncthreads();
  if (t < 64){
    double s = 0.0, q = 0.0;
    for (int x = 0; x < 16; x++){ s += red[(t*16+x)*2]; q += red[(t*16+x)*2+1]; }
    int slot = b*256 + blockIdx.x;
    mpart[((size_t)t*1024 + slot)*2] = s;
    mpart[((size_t)t*1024 + slot)*2 + 1] = q;
  }
}

__global__ void k_mask_stats(const double* __restrict__ mpart, float* __restrict__ mstat){ // <<<1,64>>>
  int t = threadIdx.x;
  double s = 0.0, q = 0.0;
  for (int i = 0; i < 1024; i++){ s += mpart[((size_t)t*1024 + i)*2]; q += mpart[((size_t)t*1024 + i)*2+1]; }
  double cnt = 65536.0;
  double mu = s/cnt; double var = q/cnt - mu*mu;
  mstat[t*2] = (float)mu; mstat[t*2+1] = 1.0f / sqrtf((float)var + 1e-5f);
}

// ---------- scores + margin ----------
__global__ __launch_bounds__(256) void k_scores(const float* __restrict__ y0, const float* __restrict__ mstat,
                                                const float* __restrict__ fg1, const float* __restrict__ fb1,
                                                const float* __restrict__ fw2, const float* __restrict__ fbias2,
                                                float* __restrict__ margin, float* __restrict__ out3){
  __shared__ float smu[64], srs[64], sg[64], sb[64], sw[128];
  int t = threadIdx.x; int b = blockIdx.y; int n = blockIdx.x*256 + t;
  if (t < 64){ smu[t] = mstat[t*2]; srs[t] = mstat[t*2+1]; sg[t] = fg1[t]; sb[t] = fb1[t]; }
  if (t < 128) sw[t] = fw2[t];
  __syncthreads();
  float a0 = 0.f, a1 = 0.f;
  const float* yb = y0 + (size_t)b*64*NPT + n;
  for (int o = 0; o < 64; o++){
    float y = yb[(size_t)o * NPT];
    float h = __fmul_rn(__fmul_rn(__fsub_rn(y, smu[o]), srs[o]), sg[o]);
    h = __fadd_rn(h, sb[o]);
    h = fmaxf(h, 0.f);
    a0 = fmaf(sw[o], h, a0);
    a1 = fmaf(sw[64+o], h, a1);
  }
  float s0 = __fadd_rn(a0, fbias2[0]);
  float s1 = __fadd_rn(a1, fbias2[1]);
  out3[(size_t)(b*2)*NPT + n] = s0;
  out3[(size_t)(b*2+1)*NPT + n] = s1;
  float m = fmaxf(s0, s1);
  float e0 = expf(__fsub_rn(s0, m));
  float e1 = expf(__fsub_rn(s1, m));
  float den = __fadd_rn(e0, e1);
  margin[b*NPT + n] = __fsub_rn(__fdiv_rn(e1, den), __fdiv_rn(e0, den));
}

// ---------- top-2048 per batch -> fg mask (radix select + ballot-scan flag phase) ----------
__global__ __launch_bounds__(1024) void k_topk(const float* __restrict__ margin, u32* __restrict__ fgmask){
  int t = threadIdx.x; int b = blockIdx.x;
  int lane = t & 63, wv = t >> 6;
  const float* mg = margin + b*NPT; u32* fm = fgmask + b*NPT;
  __shared__ int hist[256];
  __shared__ int swt[2][16];
  __shared__ u32 s_bin; __shared__ int s_need;
  int need = TOPKK; u32 prefix = 0, kmask = 0;
  for (int r = 0; r < 4; r++){
    int shift = 24 - 8*r;
    if (t < 256) hist[t] = 0;
    __syncthreads();
    for (int j = 0; j < 16; j++){
      u32 key = keyOf(mg[j*1024 + t]);
      if ((key & kmask) == prefix) atomicAdd(&hist[(key >> shift) & 255], 1);
    }
    __syncthreads();
    if (t == 0){
      int cum = 0;
      for (int bin = 255; bin >= 0; bin--){
        int c = hist[bin];
        if (cum + c >= need){ s_bin = (u32)bin; s_need = need - cum; break; }
        cum += c;
      }
    }
    __syncthreads();
    prefix |= s_bin << shift; kmask |= 255u << shift; need = s_need;
    __syncthreads();
  }
  u32 T = prefix;
  int run = 0;
  for (int j = 0; j < 16; j++){
    int n = j*1024 + t;
    u32 key = keyOf(mg[n]);
    int eq = (key == T) ? 1 : 0;
    int gt = (key > T) ? 1 : 0;
    u64 bal = __ballot(eq != 0);
    int lexcl = __popcll(bal & ((1ull << lane) - 1ull));
    if (lane == 0) swt[j & 1][wv] = __popcll(bal);
    __syncthreads();
    int base = 0, tot = 0;
    #pragma unroll
    for (int w = 0; w < 16; w++){
      int c = swt[j & 1][w];
      tot += c;
      if (w < wv) base += c;
    }
    int flag = gt | (eq & ((run + base + lexcl) < need ? 1 : 0));
    fm[n] = (u32)flag;
    run += tot;
  }
}

// ---------- compact masked candidates (stable, ascending index) ----------
__global__ __launch_bounds__(1024) void k_compact(const float* __restrict__ xyz, const u32* __restrict__ fgmask,
                                                  float* __restrict__ cx, float* __restrict__ cy,
                                                  float* __restrict__ cz, int* __restrict__ cg){
  int blk = blockIdx.x; int b = blk >> 1; int which = blk & 1;
  const float* xb = xyz + (size_t)b * NPT * 3;
  const u32* mb = fgmask + b*NPT;
  int t = threadIdx.x;
  __shared__ int sc[1024];
  u32 mloc = 0; int cnt = 0;
  int p0 = t*16;
  #pragma unroll
  for (int j = 0; j < 16; j++){
    u32 m = mb[p0+j];
    bool inc = which ? (m == 0u) : (m != 0u);
    mloc |= (inc ? 1u : 0u) << j; cnt += inc ? 1 : 0;
  }
  sc[t] = cnt; __syncthreads();
  for (int off = 1; off < 1024; off <<= 1){
    int v = (t >= off) ? sc[t-off] : 0;
    __syncthreads();
    sc[t] += v;
    __syncthreads();
  }
  int pos = sc[t] - cnt;
  int base = b*16384 + (which ? 2048 : 0);
  for (int j = 0; j < 16; j++){
    if ((mloc >> j) & 1u){
      int p = p0 + j;
      cx[base+pos] = xb[p*3]; cy[base+pos] = xb[p*3+1]; cz[base+pos] = xb[p*3+2];
      cg[base+pos] = p; pos++;
    }
  }
}

// ---------- masked FPS on compacted candidates (1024 threads) ----------
// f32 DPP wave-max -> only max lanes (~1/wave) atomicMax the full u64 key over 8
// slots; iteration-prefix keys (stale always loses), parity double-buffer, one
// barrier per iteration. Exact lowest-index tie-break via key low bits.
template<int NV>   // v2-rows per thread; candidates = NV*2048 (1024 threads)
__device__ __forceinline__ void fps_run(const float* __restrict__ cx, const float* __restrict__ cy,
                                        const float* __restrict__ cz, const int* __restrict__ cg,
                                        int b, int which,
                                        float* __restrict__ newxyz, float* __restrict__ out0,
                                        float* __restrict__ out2){
  #pragma clang fp contract(off)
  int t = threadIdx.x;
  __shared__ u64 slots[2][8];
  if (t < 16) ((u64*)slots)[t] = 0ull;
  v2 px[NV], py[NV], pz[NV], mind[NV];
  #pragma unroll
  for (int r = 0; r < NV; r++){
    int p0 = 2048*r + t, p1 = 2048*r + 1024 + t;
    px[r].x = cx[p0]; px[r].y = cx[p1];
    py[r].x = cy[p0]; py[r].y = cy[p1];
    pz[r].x = cz[p0]; pz[r].y = cz[p1];
    mind[r].x = 1e10f; mind[r].y = 1e10f;
  }
  __syncthreads();
  float bv = 1e10f; int bi = t;   // all equal -> lowest local index
  for (int it = 0; it < 512; it++){
    float wall = wave_max_f32(bv);
    if (bv == wall){
      u64 key = ((u64)(it+1) << 46) | ((u64)keyOf(bv) << 14) | (u64)(16383 - bi);
      atomicMax((unsigned long long*)&slots[it & 1][t & 7], (unsigned long long)key);
    }
    __syncthreads();
    u64 k0 = slots[it & 1][0];
    #pragma unroll
    for (int i = 1; i < 8; i++){ u64 ki = slots[it & 1][i]; if (ki > k0) k0 = ki; }
    int sel = 16383 - (int)(k0 & 0x3FFFu);
    float xs = cx[sel], ys = cy[sel], zs = cz[sel];   // uniform L2-resident load
    if (t == 0){
      int s = which*512 + it;
      out2[b*1024 + s] = (float)cg[sel];
      newxyz[(b*1024 + s)*3]   = xs;
      newxyz[(b*1024 + s)*3+1] = ys;
      newxyz[(b*1024 + s)*3+2] = zs;
      out0[(b*1024 + s)*3]   = xs;
      out0[(b*1024 + s)*3+1] = ys;
      out0[(b*1024 + s)*3+2] = zs;
    }
    v2 xs2; xs2.x = xs; xs2.y = xs;
    v2 ys2; ys2.x = ys; ys2.y = ys;
    v2 zs2; zs2.x = zs; zs2.y = zs;
    bv = -1.0f; bi = 16383;
    #pragma unroll
    for (int r = 0; r < NV; r++){
      v2 dx = px[r] - xs2;
      v2 dy = py[r] - ys2;
      v2 dz = pz[r] - zs2;
      v2 qx = dx * dx;
      v2 qy = dy * dy;
      v2 qz = dz * dz;
      v2 s1 = qx + qy;
      v2 d  = s1 + qz;
      float m0 = fminf(mind[r].x, d.x);
      float m1 = fminf(mind[r].y, d.y);
      mind[r].x = m0; mind[r].y = m1;
      if (m0 > bv){ bv = m0; bi = 2048*r + t; }
      if (m1 > bv){ bv = m1; bi = 2048*r + 1024 + t; }
    }
  }
}

__global__ __launch_bounds__(1024) void k_fps(const float* __restrict__ cx, const float* __restrict__ cy,
                                              const float* __restrict__ cz, const int* __restrict__ cg,
                                              float* __restrict__ newxyz, float* __restrict__ out0,
                                              float* __restrict__ out2){
  int b = blockIdx.x >> 1; int which = blockIdx.x & 1;
  int base = b*16384 + (which ? 2048 : 0);
  if (which) fps_run<7>(cx+base, cy+base, cz+base, cg+base, b, 1, newxyz, out0, out2);
  else       fps_run<1>(cx+base, cy+base, cz+base, cg+base, b, 0, newxyz, out0, out2);
}

// ---------- ball query: one wave per query (inclusive <=, f32 radius^2) ----------
__global__ __launch_bounds__(256) void k_ball(const float* __restrict__ xyz, const float* __restrict__ newxyz,
                                              int* __restrict__ idxnb){
  int t = threadIdx.x; int lane = t & 63;
  int qid = blockIdx.x*4 + (t >> 6);
  int b = qid >> 10;
  const float* xb = xyz + (size_t)b * NPT * 3;
  float qx = newxyz[qid*3], qy = newxyz[qid*3+1], qz = newxyz[qid*3+2];
  int found = 0, first = -1;
  for (int base = 0; base < NPT; base += 64){
    int p = base + lane;
    float x = xb[p*3], y = xb[p*3+1], z = xb[p*3+2];
    float dx = __fsub_rn(qx, x), dy = __fsub_rn(qy, y), dz = __fsub_rn(qz, z);
    float d2 = __fadd_rn(__fadd_rn(__fmul_rn(dx,dx), __fmul_rn(dy,dy)), __fmul_rn(dz,dz));
    bool w = d2 <= 0.09f;
    u64 m = __ballot(w);
    if (first < 0 && m) first = base + __ffsll((unsigned long long)m) - 1;
    if (w){
      int pos = found + __popcll(m & ((1ull << lane) - 1ull));
      if (pos < NS) idxnb[(size_t)qid*NS + pos] = p;
    }
    found += __popcll(m);
    if (found >= NS) break;
  }
  if (first < 0) first = 0;
  if (lane < NS && lane >= found) idxnb[(size_t)qid*NS + lane] = first;
}

// ---------- build grouped input Xb2 in K8-packed layout [kg][P][8] bf16 (20 kgroups, zero-padded) ----------
__global__ __launch_bounds__(256) void k_buildX(const float* __restrict__ xyz, const float* __restrict__ newxyz,
                                                const int* __restrict__ idxnb, const float* __restrict__ feat,
                                                u16* __restrict__ Xb2){
  int pos = blockIdx.x*256 + threadIdx.x;
  int b = pos >> 15; int r = pos & 32767; int s = r >> 5;
  int gi = idxnb[pos] & (NPT - 1);
  const float* xp = xyz + ((size_t)b*NPT + gi) * 3;
  const float* qp = newxyz + ((size_t)(b << 10) + s) * 3;
  float dxyz[3];
  #pragma unroll
  for (int c = 0; c < 3; c++) dxyz[c] = __fsub_rn(xp[c], qp[c]);
  const float* fb = feat + (size_t)b*CIN*NPT + gi;
  for (int g8 = 0; g8 < 20; g8++){
    u32 pk[4];
    #pragma unroll
    for (int i = 0; i < 4; i++){
      u16 v0, v1;
      int c0 = g8*8 + 2*i, c1 = c0 + 1;
      float f0 = (c0 < 3) ? dxyz[c0] : ((c0 < 131) ? fb[(size_t)(c0-3)*NPT] : 0.f);
      float f1 = (c1 < 3) ? dxyz[c1] : ((c1 < 131) ? fb[(size_t)(c1-3)*NPT] : 0.f);
      v0 = f2bf(f0); v1 = f2bf(f1);
      pk[i] = (u32)v0 | ((u32)v1 << 16);
    }
    *(uint4*)(Xb2 + ((size_t)g8*PP + pos)*8) = make_uint4(pk[0], pk[1], pk[2], pk[3]);
  }
}

// ---------- MFMA conv layer: Y[M][P] = Wb[M][Kpad] x Xp(K8) ; K8-packed bf16 out + f64 stat partials ----------
template<int NKS, int STORE>
__global__ __launch_bounds__(256) void k_mfma(const u16* __restrict__ Wb, int Kpad,
                                              const u16* __restrict__ Xp,
                                              u16* __restrict__ Yp, double* __restrict__ cpart){
  __shared__ float sred[4][16][16][2];
  int t = threadIdx.x;
  int w = t >> 6, lane = t & 63;
  int q = lane >> 4, c = lane & 15;
  int p0 = blockIdx.x * 64, m0 = blockIdx.y * 64;
  int m_w = m0 + w*16;
  f32x4 acc[4] = {{0.f,0.f,0.f,0.f},{0.f,0.f,0.f,0.f},{0.f,0.f,0.f,0.f},{0.f,0.f,0.f,0.f}};
  const u16* arow = Wb + (size_t)(m_w + c) * Kpad + q*8;
  #pragma unroll
  for (int ks = 0; ks < NKS; ks++){
    bf16x8 afrag = *(const bf16x8*)(arow + ks*32);
    #pragma unroll
    for (int pp = 0; pp < 4; pp++){
      int p = p0 + pp*16 + c;
      bf16x8 bfrag = *(const bf16x8*)(Xp + (((size_t)(ks*4 + q) * PP) + p) * 8);
      acc[pp] = __builtin_amdgcn_mfma_f32_16x16x32_bf16(afrag, bfrag, acc[pp], 0, 0, 0);
    }
  }
  #pragma unroll
  for (int reg = 0; reg < 4; reg++){
    float s = 0.f, sq = 0.f;
    #pragma unroll
    for (int pp = 0; pp < 4; pp++){ float v = acc[pp][reg]; s += v; sq += v*v; }
    sred[w][q*4+reg][c][0] = s; sred[w][q*4+reg][c][1] = sq;
  }
  if (STORE){
    int kgm = (m_w + q*4) >> 3;
    int j0 = (m_w + q*4) & 7;
    #pragma unroll
    for (int pp = 0; pp < 4; pp++){
      int p = p0 + pp*16 + c;
      ushort4 pk;
      pk.x = f2bf(acc[pp][0]); pk.y = f2bf(acc[pp][1]); pk.z = f2bf(acc[pp][2]); pk.w = f2bf(acc[pp][3]);
      *(ushort4*)(Yp + (((size_t)kgm * PP) + p) * 8 + j0) = pk;
    }
  }
  __syncthreads();
  if (t < 64){
    int ww = t >> 4, ml = t & 15;
    double s = 0.0, qq = 0.0;
    for (int cc = 0; cc < 16; cc++){ s += sred[ww][ml][cc][0]; qq += sred[ww][ml][cc][1]; }
    cpart[((size_t)(m0 + t) * 2048 + blockIdx.x)*2] = s;
    cpart[((size_t)(m0 + t) * 2048 + blockIdx.x)*2 + 1] = qq;
  }
}

__global__ __launch_bounds__(256) void k_stats_conv(const double* __restrict__ cpart,
                                                    const float* __restrict__ g, const float* __restrict__ bt,
                                                    float2* __restrict__ ssv){
  __shared__ double rs_[256], rq_[256];
  int ch = blockIdx.x, t = threadIdx.x;
  double s = 0.0, q = 0.0;
  for (int i = t; i < 2048; i += 256){ s += cpart[((size_t)ch*2048 + i)*2]; q += cpart[((size_t)ch*2048 + i)*2+1]; }
  rs_[t] = s; rq_[t] = q; __syncthreads();
  for (int off = 128; off; off >>= 1){
    if (t < off){ rs_[t] += rs_[t+off]; rq_[t] += rq_[t+off]; }
    __syncthreads();
  }
  if (t == 0){
    double cnt = (double)PP;
    double mu = rs_[0]/cnt; double var = rq_[0]/cnt - mu*mu;
    float rsf = 1.0f / sqrtf((float)var + 1e-5f);
    double rsd = (double)rsf;
    double gd = (double)g[ch]; double bd = (double)bt[ch];
    ssv[ch] = make_float2((float)(rsd*gd), (float)(bd - mu*rsd*gd));
  }
}

// ---------- elementwise BN affine + relu, in place on K8-packed bf16 (16 kgroups) ----------
__global__ __launch_bounds__(256) void k_affine(u16* __restrict__ y, const float2* __restrict__ aff){
  int tid = blockIdx.x*256 + threadIdx.x;
  int kg = tid >> 17; int p = tid & (PP - 1);
  uint4* ptr = (uint4*)(y + (((size_t)kg*PP) + p)*8);
  uint4 u = *ptr;
  u32 us[4] = {u.x, u.y, u.z, u.w};
  u32 outp[4];
  #pragma unroll
  for (int i = 0; i < 4; i++){
    float2 a0 = aff[kg*8 + 2*i], a1 = aff[kg*8 + 2*i + 1];
    float v0 = fmaxf(0.f, fmaf(bf2f(us[i] & 0xFFFFu), a0.x, a0.y));
    float v1 = fmaxf(0.f, fmaf(bf2f(us[i] >> 16),     a1.x, a1.y));
    outp[i] = (u32)f2bf(v0) | ((u32)f2bf(v1) << 16);
  }
  *ptr = make_uint4(outp[0], outp[1], outp[2], outp[3]);
}

// ---------- fused layer-3 recompute + BN3 + relu + maxpool (one block per query; Y2a is affined K8) ----------
__global__ __launch_bounds__(256) void k_fuse3pool(const u16* __restrict__ Y2a, const float* __restrict__ wt3f,
                                                   const float2* __restrict__ ss2, float* __restrict__ out1){
  __shared__ float Xs[128*36];
  int t = threadIdx.x;
  int qid = blockIdx.x;          // b*1024 + s
  int b = qid >> 10, s = qid & 1023;
  size_t cb = (size_t)qid << 5;
  #pragma unroll
  for (int e = 0; e < 2; e++){
    int lin = e*256 + t; int kg = lin >> 5, j = lin & 31;
    uint4 u = *(const uint4*)(Y2a + ((size_t)kg*PP + cb + j)*8);
    u32 us[4] = {u.x, u.y, u.z, u.w};
    #pragma unroll
    for (int i = 0; i < 4; i++){
      Xs[(kg*8 + 2*i    )*36 + j] = bf2f(us[i] & 0xFFFFu);
      Xs[(kg*8 + 2*i + 1)*36 + j] = bf2f(us[i] >> 16);
    }
  }
  __syncthreads();
  float acc[32] = {};
  for (int k = 0; k < 128; k++){
    float w = wt3f[k*256 + t];
    const float4* xr = (const float4*)&Xs[k*36];
    #pragma unroll
    for (int jq = 0; jq < 8; jq++){
      float4 x = xr[jq];
      acc[jq*4+0] = fmaf(w, x.x, acc[jq*4+0]);
      acc[jq*4+1] = fmaf(w, x.y, acc[jq*4+1]);
      acc[jq*4+2] = fmaf(w, x.z, acc[jq*4+2]);
      acc[jq*4+3] = fmaf(w, x.w, acc[jq*4+3]);
    }
  }
  float2 a2 = ss2[t];
  float mx = 0.f;
  #pragma unroll
  for (int j = 0; j < 32; j++) mx = fmaxf(mx, fmaxf(0.f, fmaf(acc[j], a2.x, a2.y)));
  out1[((size_t)b << 18) + (size_t)t*1024 + s] = mx;
}

extern "C" void kernel_launch(void* const* d_in, const int* in_sizes, int n_in,
                              void* d_out, int out_size, void* d_ws, size_t ws_size,
                              hipStream_t stream){
  (void)in_sizes; (void)n_in; (void)out_size;
  if (ws_size < WS_NEED) return;
  const float* xyz    = (const float*)d_in[0];
  const float* feat   = (const float*)d_in[1];
  const float* w1     = (const float*)d_in[2];
  const float* g1     = (const float*)d_in[3];
  const float* b1     = (const float*)d_in[4];
  const float* w2     = (const float*)d_in[5];
  const float* g2     = (const float*)d_in[6];
  const float* b2     = (const float*)d_in[7];
  const float* w3     = (const float*)d_in[8];
  const float* g3     = (const float*)d_in[9];
  const float* b3     = (const float*)d_in[10];
  const float* fw1    = (const float*)d_in[11];
  const float* fg1    = (const float*)d_in[12];
  const float* fb1    = (const float*)d_in[13];
  const float* fw2    = (const float*)d_in[14];
  const float* fbias2 = (const float*)d_in[15];

  char* ws = (char*)d_ws;
  float*  newxyz = (float*)(ws + OFF_NEWXYZ);
  float*  margin = (float*)(ws + OFF_MARGIN);
  u32*    fgmask = (u32*)(ws + OFF_FGMASK);
  int*    idxnb  = (int*)(ws + OFF_IDXNB);
  float*  mstat  = (float*)(ws + OFF_MSTAT);
  float2* ss0    = (float2*)(ws + OFF_SSA);
  float2* ss1    = ss0 + 128;
  float2* ss2    = ss0 + 256;
  float*  wt0    = (float*)(ws + OFF_WT0);
  u16*    w1b    = (u16*)(ws + OFF_W1B);
  u16*    w2b    = (u16*)(ws + OFF_W2B);
  u16*    w3b    = (u16*)(ws + OFF_W3B);
  float*  wt3f   = (float*)(ws + OFF_WT3F);
  double* mpart  = (double*)(ws + OFF_MPART);
  double* cpart  = (double*)(ws + OFF_CPART);
  u16*    Y1p    = (u16*)(ws + OFF_REGB);     // 32 MB K8 bf16
  // Region A phases: y0 (16MB f32) -> cx/cy/cz/cg (1MB) -> Xb2 (40MB K8) -> Y2p (32MB K8)
  float*  y0     = (float*)(ws + OFF_REGA);
  float*  cx     = (float*)(ws + OFF_REGA);
  float*  cy     = cx + 4*16384;
  float*  cz     = cy + 4*16384;
  int*    cg     = (int*)(cz + 4*16384);
  u16*    Xb2    = (u16*)(ws + OFF_REGA);
  u16*    Y2p    = (u16*)(ws + OFF_REGA);

  float* out  = (float*)d_out;
  float* out0 = out;            // [4,1024,3]
  float* out1 = out + 12288;    // [4,256,1024]
  float* out2 = out + 1060864;  // [4,1024]
  float* out3 = out + 1064960;  // [4,2,16384]

  k_prep<<<dim3(256), dim3(256), 0, stream>>>(w1, w2, w3, fw1, wt0, w1b, w2b, w3b, wt3f);
  k_gemm_mask<<<dim3(256,1,4), dim3(256), 0, stream>>>(wt0, feat, y0, mpart);
  k_mask_stats<<<dim3(1), dim3(64), 0, stream>>>(mpart, mstat);
  k_scores<<<dim3(64,4), dim3(256), 0, stream>>>(y0, mstat, fg1, fb1, fw2, fbias2, margin, out3);
  k_topk<<<dim3(4), dim3(1024), 0, stream>>>(margin, fgmask);
  k_compact<<<dim3(8), dim3(1024), 0, stream>>>(xyz, fgmask, cx, cy, cz, cg);
  k_fps<<<dim3(8), dim3(1024), 0, stream>>>(cx, cy, cz, cg, newxyz, out0, out2);
  k_ball<<<dim3(1024), dim3(256), 0, stream>>>(xyz, newxyz, idxnb);
  k_buildX<<<dim3(512), dim3(256), 0, stream>>>(xyz, newxyz, idxnb, feat, Xb2);
  k_mfma<5,1><<<dim3(2048,2), dim3(256), 0, stream>>>(w1b, 160, Xb2, Y1p, cpart);
  k_stats_conv<<<dim3(128), dim3(256), 0, stream>>>(cpart, g1, b1, ss0);
  k_affine<<<dim3(8192), dim3(256), 0, stream>>>(Y1p, ss0);
  k_mfma<4,1><<<dim3(2048,2), dim3(256), 0, stream>>>(w2b, 128, Y1p, Y2p, cpart);
  k_stats_conv<<<dim3(128), dim3(256), 0, stream>>>(cpart, g2, b2, ss1);
  k_affine<<<dim3(8192), dim3(256), 0, stream>>>(Y2p, ss1);
  k_mfma<4,0><<<dim3(2048,4), dim3(256), 0, stream>>>(w3b, 128, Y2p, (u16*)nullptr, cpart);
  k_stats_conv<<<dim3(256), dim3(256), 0, stream>>>(cpart, g3, b3, ss2);
  k_fuse3pool<<<dim3(4096), dim3(256), 0, stream>>>(Y2p, wt3f, ss2, out1);
}

// Round 10
// 1232.823 us; speedup vs baseline: 1.1805x; 1.1047x over previous
//
#include <hip/hip_runtime.h>

#define BB 4
#define NPT 16384
#define CIN 128
#define SS 1024
#define NS 32
#define PP 131072   // BB*SS*NS
#define TOPKK 2048

typedef unsigned short u16;
typedef unsigned int u32;
typedef unsigned long long u64;
typedef float v2 __attribute__((ext_vector_type(2)));
typedef short bf16x8 __attribute__((ext_vector_type(8)));
typedef float f32x4 __attribute__((ext_vector_type(4)));

// ---------- helpers ----------
__device__ __forceinline__ float bf2f(u32 v){ return __uint_as_float(v << 16); }
__device__ __forceinline__ u16 f2bf(float f){
  u32 u = __float_as_uint(f);
  u32 r = (u + 0x7FFFu + ((u >> 16) & 1u)) >> 16;   // RNE
  return (u16)r;
}
__device__ __forceinline__ u32 keyOf(float m){
  u32 u = __float_as_uint(m);
  return (u & 0x80000000u) ? ~u : (u | 0x80000000u);  // monotone in float order
}

// f32 wave64 max via DPP, broadcast to all lanes. bound_ctrl=1 fills 0 (inputs >= 0).
__device__ __forceinline__ float wave_max_f32(float v){
  #define STEP(CTRL) { int o_ = __builtin_amdgcn_update_dpp(0, __float_as_int(v), CTRL, 0xf, 0xf, true); \
                       v = fmaxf(v, __int_as_float(o_)); }
  STEP(0x111) STEP(0x112) STEP(0x114) STEP(0x118)  // row_shr 1,2,4,8
  STEP(0x142) STEP(0x143)                           // row_bcast 15, 31 -> lane63 = wave max
  #undef STEP
  return __int_as_float(__builtin_amdgcn_readlane(__float_as_int(v), 63));
}

// f32 max over each 16-lane row (lane c=15 of the row holds the result). values >= 0.
__device__ __forceinline__ float row_max16(float v){
  #define STEP(CTRL) { int o_ = __builtin_amdgcn_update_dpp(0, __float_as_int(v), CTRL, 0xf, 0xf, true); \
                       v = fmaxf(v, __int_as_float(o_)); }
  STEP(0x111) STEP(0x112) STEP(0x114) STEP(0x118)
  #undef STEP
  return v;
}

// ---------- ws layout (bytes) — total 86,342,144 (82.3 MB) ----------
#define OFF_NEWXYZ 0ull                 // B*S*3 f32        49152
#define OFF_MARGIN 49152ull             // B*N f32          262144
#define OFF_FGMASK 311296ull            // B*N u32          262144
#define OFF_IDXNB  573440ull            // B*S*NS i32       524288
#define OFF_MSTAT  1097728ull           // 64*2 f32         512
#define OFF_SSA    1098240ull           // 512 float2       6144 (ss0:128, ss1:128, ss2:256)
#define OFF_WT0    1104384ull           // 128*64 f32       32768
#define OFF_W1B    1137152ull           // 128*160 bf16     40960
#define OFF_W2B    1178112ull           // 128*128 bf16     32768
#define OFF_W3B    1210880ull           // 256*128 bf16     65536
#define OFF_MPART  1407488ull           // 64*1024*2 f64    1048576
#define OFF_CPART  2456064ull           // 256*2048*2 f64   8388608
#define OFF_REGB   10844672ull          // Y1p 32MB bf16 (K8)
#define OFF_REGA   44399104ull          // y0(16MB) -> cxyz(1MB) -> Xb2(40MB K8) -> Y2p(32MB K8)
#define WS_NEED    86342144ull

// ---------- prep: weights (fp32 mask-head; bf16 [M][Kpad] for MFMA) ----------
__global__ void k_prep(const float* __restrict__ w1, const float* __restrict__ w2,
                       const float* __restrict__ w3, const float* __restrict__ fw1,
                       float* __restrict__ wt0, u16* __restrict__ w1b, u16* __restrict__ w2b,
                       u16* __restrict__ w3b){
  int gt = blockIdx.x*blockDim.x + threadIdx.x;
  int gs = gridDim.x*blockDim.x;
  for (int i = gt; i < 128*64;  i += gs){ int k=i>>6, m=i&63;  wt0[i] = fw1[m*128+k]; }
  for (int i = gt; i < 128*160; i += gs){ int m=i/160, k=i-m*160; w1b[i] = (k<131)? f2bf(w1[m*131+k]) : (u16)0; }
  for (int i = gt; i < 128*128; i += gs){ w2b[i] = f2bf(w2[i]); }
  for (int i = gt; i < 256*128; i += gs){ w3b[i] = f2bf(w3[i]); }
}

// ---------- mask-head GEMM (fp32 exact path): y0[b][64][N] + deterministic stat partials ----------
__global__ __launch_bounds__(256) void k_gemm_mask(const float* __restrict__ Wt,    // [128][64]
                                                   const float* __restrict__ feat,  // [B][128][N] f32
                                                   float* __restrict__ y0,
                                                   double* __restrict__ mpart){     // [64][1024][2]
  __shared__ float As[32][64];
  __shared__ float Bs[32][64];
  int t = threadIdx.x, tx = t & 15, ty = t >> 4;
  int p0 = blockIdx.x * 64; int b = blockIdx.z;
  const float* X = feat + (size_t)b * CIN * NPT;
  float acc[4][4] = {};
  int e = t * 8, ka = e >> 6, ca = e & 63;
  for (int kc = 0; kc < 4; kc++){
    const float* wr = Wt + (size_t)(kc*32 + ka) * 64 + ca;
    float4 w0 = *(const float4*)wr;
    float4 w1v = *(const float4*)(wr + 4);
    const float* br = X + (size_t)(kc*32 + ka) * NPT + p0 + ca;
    float4 b0 = *(const float4*)br;
    float4 b1 = *(const float4*)(br + 4);
    __syncthreads();
    *(float4*)&As[ka][ca] = w0; *(float4*)&As[ka][ca+4] = w1v;
    *(float4*)&Bs[ka][ca] = b0; *(float4*)&Bs[ka][ca+4] = b1;
    __syncthreads();
    #pragma unroll
    for (int k = 0; k < 32; k++){
      float4 a = *(float4*)&As[k][ty*4];
      float4 bq = *(float4*)&Bs[k][tx*4];
      float av[4] = {a.x,a.y,a.z,a.w}; float bw[4] = {bq.x,bq.y,bq.z,bq.w};
      #pragma unroll
      for (int i = 0; i < 4; i++)
        #pragma unroll
        for (int j = 0; j < 4; j++) acc[i][j] = fmaf(av[i], bw[j], acc[i][j]);
    }
  }
  #pragma unroll
  for (int i = 0; i < 4; i++){
    int m = ty*4 + i;
    float4 v = make_float4(acc[i][0], acc[i][1], acc[i][2], acc[i][3]);
    *(float4*)(y0 + ((size_t)(b*64 + m)) * NPT + p0 + tx*4) = v;
  }
  __syncthreads();
  float* red = (float*)As;
  #pragma unroll
  for (int i = 0; i < 4; i++){
    float s = 0.f, q = 0.f;
    #pragma unroll
    for (int j = 0; j < 4; j++){ s += acc[i][j]; q += acc[i][j]*acc[i][j]; }
    red[((ty*4+i)*16 + tx)*2] = s; red[((ty*4+i)*16 + tx)*2 + 1] = q;
  }
  __syncthreads();
  if (t < 64){
    double s = 0.0, q = 0.0;
    for (int x = 0; x < 16; x++){ s += red[(t*16+x)*2]; q += red[(t*16+x)*2+1]; }
    int slot = b*256 + blockIdx.x;
    mpart[((size_t)t*1024 + slot)*2] = s;
    mpart[((size_t)t*1024 + slot)*2 + 1] = q;
  }
}

__global__ void k_mask_stats(const double* __restrict__ mpart, float* __restrict__ mstat){ // <<<1,64>>>
  int t = threadIdx.x;
  double s = 0.0, q = 0.0;
  for (int i = 0; i < 1024; i++){ s += mpart[((size_t)t*1024 + i)*2]; q += mpart[((size_t)t*1024 + i)*2+1]; }
  double cnt = 65536.0;
  double mu = s/cnt; double var = q/cnt - mu*mu;
  mstat[t*2] = (float)mu; mstat[t*2+1] = 1.0f / sqrtf((float)var + 1e-5f);
}

// ---------- scores + margin ----------
__global__ __launch_bounds__(256) void k_scores(const float* __restrict__ y0, const float* __restrict__ mstat,
                                                const float* __restrict__ fg1, const float* __restrict__ fb1,
                                                const float* __restrict__ fw2, const float* __restrict__ fbias2,
                                                float* __restrict__ margin, float* __restrict__ out3){
  __shared__ float smu[64], srs[64], sg[64], sb[64], sw[128];
  int t = threadIdx.x; int b = blockIdx.y; int n = blockIdx.x*256 + t;
  if (t < 64){ smu[t] = mstat[t*2]; srs[t] = mstat[t*2+1]; sg[t] = fg1[t]; sb[t] = fb1[t]; }
  if (t < 128) sw[t] = fw2[t];
  __syncthreads();
  float a0 = 0.f, a1 = 0.f;
  const float* yb = y0 + (size_t)b*64*NPT + n;
  for (int o = 0; o < 64; o++){
    float y = yb[(size_t)o * NPT];
    float h = __fmul_rn(__fmul_rn(__fsub_rn(y, smu[o]), srs[o]), sg[o]);
    h = __fadd_rn(h, sb[o]);
    h = fmaxf(h, 0.f);
    a0 = fmaf(sw[o], h, a0);
    a1 = fmaf(sw[64+o], h, a1);
  }
  float s0 = __fadd_rn(a0, fbias2[0]);
  float s1 = __fadd_rn(a1, fbias2[1]);
  out3[(size_t)(b*2)*NPT + n] = s0;
  out3[(size_t)(b*2+1)*NPT + n] = s1;
  float m = fmaxf(s0, s1);
  float e0 = expf(__fsub_rn(s0, m));
  float e1 = expf(__fsub_rn(s1, m));
  float den = __fadd_rn(e0, e1);
  margin[b*NPT + n] = __fsub_rn(__fdiv_rn(e1, den), __fdiv_rn(e0, den));
}

// ---------- top-2048 per batch -> fg mask (radix select + ballot-scan flag phase) ----------
__global__ __launch_bounds__(1024) void k_topk(const float* __restrict__ margin, u32* __restrict__ fgmask){
  int t = threadIdx.x; int b = blockIdx.x;
  int lane = t & 63, wv = t >> 6;
  const float* mg = margin + b*NPT; u32* fm = fgmask + b*NPT;
  __shared__ int hist[256];
  __shared__ int swt[2][16];
  __shared__ u32 s_bin; __shared__ int s_need;
  int need = TOPKK; u32 prefix = 0, kmask = 0;
  for (int r = 0; r < 4; r++){
    int shift = 24 - 8*r;
    if (t < 256) hist[t] = 0;
    __syncthreads();
    for (int j = 0; j < 16; j++){
      u32 key = keyOf(mg[j*1024 + t]);
      if ((key & kmask) == prefix) atomicAdd(&hist[(key >> shift) & 255], 1);
    }
    __syncthreads();
    if (t == 0){
      int cum = 0;
      for (int bin = 255; bin >= 0; bin--){
        int c = hist[bin];
        if (cum + c >= need){ s_bin = (u32)bin; s_need = need - cum; break; }
        cum += c;
      }
    }
    __syncthreads();
    prefix |= s_bin << shift; kmask |= 255u << shift; need = s_need;
    __syncthreads();
  }
  u32 T = prefix;
  int run = 0;
  for (int j = 0; j < 16; j++){
    int n = j*1024 + t;
    u32 key = keyOf(mg[n]);
    int eq = (key == T) ? 1 : 0;
    int gt = (key > T) ? 1 : 0;
    u64 bal = __ballot(eq != 0);
    int lexcl = __popcll(bal & ((1ull << lane) - 1ull));
    if (lane == 0) swt[j & 1][wv] = __popcll(bal);
    __syncthreads();
    int base = 0, tot = 0;
    #pragma unroll
    for (int w = 0; w < 16; w++){
      int c = swt[j & 1][w];
      tot += c;
      if (w < wv) base += c;
    }
    int flag = gt | (eq & ((run + base + lexcl) < need ? 1 : 0));
    fm[n] = (u32)flag;
    run += tot;
  }
}

// ---------- compact masked candidates (stable, ascending index) ----------
__global__ __launch_bounds__(1024) void k_compact(const float* __restrict__ xyz, const u32* __restrict__ fgmask,
                                                  float* __restrict__ cx, float* __restrict__ cy,
                                                  float* __restrict__ cz, int* __restrict__ cg){
  int blk = blockIdx.x; int b = blk >> 1; int which = blk & 1;
  const float* xb = xyz + (size_t)b * NPT * 3;
  const u32* mb = fgmask + b*NPT;
  int t = threadIdx.x;
  __shared__ int sc[1024];
  u32 mloc = 0; int cnt = 0;
  int p0 = t*16;
  #pragma unroll
  for (int j = 0; j < 16; j++){
    u32 m = mb[p0+j];
    bool inc = which ? (m == 0u) : (m != 0u);
    mloc |= (inc ? 1u : 0u) << j; cnt += inc ? 1 : 0;
  }
  sc[t] = cnt; __syncthreads();
  for (int off = 1; off < 1024; off <<= 1){
    int v = (t >= off) ? sc[t-off] : 0;
    __syncthreads();
    sc[t] += v;
    __syncthreads();
  }
  int pos = sc[t] - cnt;
  int base = b*16384 + (which ? 2048 : 0);
  for (int j = 0; j < 16; j++){
    if ((mloc >> j) & 1u){
      int p = p0 + j;
      cx[base+pos] = xb[p*3]; cy[base+pos] = xb[p*3+1]; cz[base+pos] = xb[p*3+2];
      cg[base+pos] = p; pos++;
    }
  }
}

// ---------- masked FPS (512 threads): f32 DPP wave-max -> sparse u64 atomicMax over 8 slots ----------
// Iteration-prefix keys make stale entries lose (no resets); parity double-buffer,
// single barrier per iteration. Exact lowest-index tie-break via key low bits.
template<int NV>   // v2-rows per thread; candidates = NV*1024 (512 threads)
__device__ __forceinline__ void fps_run(const float* __restrict__ cx, const float* __restrict__ cy,
                                        const float* __restrict__ cz, const int* __restrict__ cg,
                                        int b, int which,
                                        float* __restrict__ newxyz, float* __restrict__ out0,
                                        float* __restrict__ out2){
  #pragma clang fp contract(off)
  int t = threadIdx.x;
  __shared__ u64 slots[2][8];
  if (t < 16) ((u64*)slots)[t] = 0ull;
  v2 px[NV], py[NV], pz[NV], mind[NV];
  #pragma unroll
  for (int r = 0; r < NV; r++){
    int p0 = 1024*r + t, p1 = 1024*r + 512 + t;
    px[r].x = cx[p0]; px[r].y = cx[p1];
    py[r].x = cy[p0]; py[r].y = cy[p1];
    pz[r].x = cz[p0]; pz[r].y = cz[p1];
    mind[r].x = 1e10f; mind[r].y = 1e10f;
  }
  __syncthreads();
  float bv = 1e10f; int bi = t;   // all equal -> lowest local index
  for (int it = 0; it < 512; it++){
    float wall = wave_max_f32(bv);
    if (bv == wall){
      u64 key = ((u64)(it+1) << 46) | ((u64)keyOf(bv) << 14) | (u64)(16383 - bi);
      atomicMax((unsigned long long*)&slots[it & 1][t & 7], (unsigned long long)key);
    }
    __syncthreads();
    u64 k0 = slots[it & 1][0];
    #pragma unroll
    for (int i = 1; i < 8; i++){ u64 ki = slots[it & 1][i]; if (ki > k0) k0 = ki; }
    int sel = 16383 - (int)(k0 & 0x3FFFu);
    float xs = cx[sel], ys = cy[sel], zs = cz[sel];   // uniform L2-resident load
    if (t == 0){
      int s = which*512 + it;
      out2[b*1024 + s] = (float)cg[sel];
      newxyz[(b*1024 + s)*3]   = xs;
      newxyz[(b*1024 + s)*3+1] = ys;
      newxyz[(b*1024 + s)*3+2] = zs;
      out0[(b*1024 + s)*3]   = xs;
      out0[(b*1024 + s)*3+1] = ys;
      out0[(b*1024 + s)*3+2] = zs;
    }
    v2 xs2; xs2.x = xs; xs2.y = xs;
    v2 ys2; ys2.x = ys; ys2.y = ys;
    v2 zs2; zs2.x = zs; zs2.y = zs;
    bv = -1.0f; bi = 16383;
    #pragma unroll
    for (int r = 0; r < NV; r++){
      v2 dx = px[r] - xs2;
      v2 dy = py[r] - ys2;
      v2 dz = pz[r] - zs2;
      v2 qx = dx * dx;
      v2 qy = dy * dy;
      v2 qz = dz * dz;
      v2 s1 = qx + qy;
      v2 d  = s1 + qz;
      float m0 = fminf(mind[r].x, d.x);
      float m1 = fminf(mind[r].y, d.y);
      mind[r].x = m0; mind[r].y = m1;
      if (m0 > bv){ bv = m0; bi = 1024*r + t; }
      if (m1 > bv){ bv = m1; bi = 1024*r + 512 + t; }
    }
  }
}

__global__ __launch_bounds__(512) void k_fps(const float* __restrict__ cx, const float* __restrict__ cy,
                                             const float* __restrict__ cz, const int* __restrict__ cg,
                                             float* __restrict__ newxyz, float* __restrict__ out0,
                                             float* __restrict__ out2){
  int b = blockIdx.x >> 1; int which = blockIdx.x & 1;
  int base = b*16384 + (which ? 2048 : 0);
  if (which) fps_run<14>(cx+base, cy+base, cz+base, cg+base, b, 1, newxyz, out0, out2);
  else       fps_run<2 >(cx+base, cy+base, cz+base, cg+base, b, 0, newxyz, out0, out2);
}

// ---------- ball query: one wave per query (inclusive <=, f32 radius^2) ----------
__global__ __launch_bounds__(256) void k_ball(const float* __restrict__ xyz, const float* __restrict__ newxyz,
                                              int* __restrict__ idxnb){
  int t = threadIdx.x; int lane = t & 63;
  int qid = blockIdx.x*4 + (t >> 6);
  int b = qid >> 10;
  const float* xb = xyz + (size_t)b * NPT * 3;
  float qx = newxyz[qid*3], qy = newxyz[qid*3+1], qz = newxyz[qid*3+2];
  int found = 0, first = -1;
  for (int base = 0; base < NPT; base += 64){
    int p = base + lane;
    float x = xb[p*3], y = xb[p*3+1], z = xb[p*3+2];
    float dx = __fsub_rn(qx, x), dy = __fsub_rn(qy, y), dz = __fsub_rn(qz, z);
    float d2 = __fadd_rn(__fadd_rn(__fmul_rn(dx,dx), __fmul_rn(dy,dy)), __fmul_rn(dz,dz));
    bool w = d2 <= 0.09f;
    u64 m = __ballot(w);
    if (first < 0 && m) first = base + __ffsll((unsigned long long)m) - 1;
    if (w){
      int pos = found + __popcll(m & ((1ull << lane) - 1ull));
      if (pos < NS) idxnb[(size_t)qid*NS + pos] = p;
    }
    found += __popcll(m);
    if (found >= NS) break;
  }
  if (first < 0) first = 0;
  if (lane < NS && lane >= found) idxnb[(size_t)qid*NS + lane] = first;
}

// ---------- build grouped input Xb2 in K8-packed layout [kg][P][8] bf16 (20 kgroups, zero-padded) ----------
__global__ __launch_bounds__(256) void k_buildX(const float* __restrict__ xyz, const float* __restrict__ newxyz,
                                                const int* __restrict__ idxnb, const float* __restrict__ feat,
                                                u16* __restrict__ Xb2){
  int pos = blockIdx.x*256 + threadIdx.x;
  int b = pos >> 15; int r = pos & 32767; int s = r >> 5;
  int gi = idxnb[pos] & (NPT - 1);
  const float* xp = xyz + ((size_t)b*NPT + gi) * 3;
  const float* qp = newxyz + ((size_t)(b << 10) + s) * 3;
  float dxyz[3];
  #pragma unroll
  for (int c = 0; c < 3; c++) dxyz[c] = __fsub_rn(xp[c], qp[c]);
  const float* fb = feat + (size_t)b*CIN*NPT + gi;
  for (int g8 = 0; g8 < 20; g8++){
    u32 pk[4];
    #pragma unroll
    for (int i = 0; i < 4; i++){
      int c0 = g8*8 + 2*i, c1 = c0 + 1;
      float f0 = (c0 < 3) ? dxyz[c0] : ((c0 < 131) ? fb[(size_t)(c0-3)*NPT] : 0.f);
      float f1 = (c1 < 3) ? dxyz[c1] : ((c1 < 131) ? fb[(size_t)(c1-3)*NPT] : 0.f);
      pk[i] = (u32)f2bf(f0) | ((u32)f2bf(f1) << 16);
    }
    *(uint4*)(Xb2 + ((size_t)g8*PP + pos)*8) = make_uint4(pk[0], pk[1], pk[2], pk[3]);
  }
}

// ---------- MFMA conv layer: Y[M][P] = Wb[M][Kpad] x Xp(K8) ; K8-packed bf16 out + f64 stat partials ----------
template<int NKS, int STORE>
__global__ __launch_bounds__(256) void k_mfma(const u16* __restrict__ Wb, int Kpad,
                                              const u16* __restrict__ Xp,
                                              u16* __restrict__ Yp, double* __restrict__ cpart){
  __shared__ float sred[4][16][16][2];
  int t = threadIdx.x;
  int w = t >> 6, lane = t & 63;
  int q = lane >> 4, c = lane & 15;
  int p0 = blockIdx.x * 64, m0 = blockIdx.y * 64;
  int m_w = m0 + w*16;
  f32x4 acc[4] = {{0.f,0.f,0.f,0.f},{0.f,0.f,0.f,0.f},{0.f,0.f,0.f,0.f},{0.f,0.f,0.f,0.f}};
  const u16* arow = Wb + (size_t)(m_w + c) * Kpad + q*8;
  #pragma unroll
  for (int ks = 0; ks < NKS; ks++){
    bf16x8 afrag = *(const bf16x8*)(arow + ks*32);
    #pragma unroll
    for (int pp = 0; pp < 4; pp++){
      int p = p0 + pp*16 + c;
      bf16x8 bfrag = *(const bf16x8*)(Xp + (((size_t)(ks*4 + q) * PP) + p) * 8);
      acc[pp] = __builtin_amdgcn_mfma_f32_16x16x32_bf16(afrag, bfrag, acc[pp], 0, 0, 0);
    }
  }
  #pragma unroll
  for (int reg = 0; reg < 4; reg++){
    float s = 0.f, sq = 0.f;
    #pragma unroll
    for (int pp = 0; pp < 4; pp++){ float v = acc[pp][reg]; s += v; sq += v*v; }
    sred[w][q*4+reg][c][0] = s; sred[w][q*4+reg][c][1] = sq;
  }
  if (STORE){
    int kgm = (m_w + q*4) >> 3;
    int j0 = (m_w + q*4) & 7;
    #pragma unroll
    for (int pp = 0; pp < 4; pp++){
      int p = p0 + pp*16 + c;
      ushort4 pk;
      pk.x = f2bf(acc[pp][0]); pk.y = f2bf(acc[pp][1]); pk.z = f2bf(acc[pp][2]); pk.w = f2bf(acc[pp][3]);
      *(ushort4*)(Yp + (((size_t)kgm * PP) + p) * 8 + j0) = pk;
    }
  }
  __syncthreads();
  if (t < 64){
    int ww = t >> 4, ml = t & 15;
    double s = 0.0, qq = 0.0;
    for (int cc = 0; cc < 16; cc++){ s += sred[ww][ml][cc][0]; qq += sred[ww][ml][cc][1]; }
    cpart[((size_t)(m0 + t) * 2048 + blockIdx.x)*2] = s;
    cpart[((size_t)(m0 + t) * 2048 + blockIdx.x)*2 + 1] = qq;
  }
}

// ---------- layer-3 recompute via MFMA + BN3 affine + relu + maxpool epilogue (no Y3 store) ----------
__global__ __launch_bounds__(256) void k_mfma_pool(const u16* __restrict__ Wb,       // w3b [256][128]
                                                   const u16* __restrict__ Xp,       // affined Y2 (K8)
                                                   const float2* __restrict__ ss2,
                                                   float* __restrict__ out1){
  int t = threadIdx.x;
  int w = t >> 6, lane = t & 63;
  int q = lane >> 4, c = lane & 15;
  int p0 = blockIdx.x * 64, m0 = blockIdx.y * 64;
  int m_w = m0 + w*16;
  f32x4 acc[4] = {{0.f,0.f,0.f,0.f},{0.f,0.f,0.f,0.f},{0.f,0.f,0.f,0.f},{0.f,0.f,0.f,0.f}};
  const u16* arow = Wb + (size_t)(m_w + c) * 128 + q*8;
  #pragma unroll
  for (int ks = 0; ks < 4; ks++){
    bf16x8 afrag = *(const bf16x8*)(arow + ks*32);
    #pragma unroll
    for (int pp = 0; pp < 4; pp++){
      int p = p0 + pp*16 + c;
      bf16x8 bfrag = *(const bf16x8*)(Xp + (((size_t)(ks*4 + q) * PP) + p) * 8);
      acc[pp] = __builtin_amdgcn_mfma_f32_16x16x32_bf16(afrag, bfrag, acc[pp], 0, 0, 0);
    }
  }
  // epilogue: affine+relu, max over pp-pairs (query halves), then DPP row-max over 16 c-lanes
  int qid0 = blockIdx.x*2;
  #pragma unroll
  for (int reg = 0; reg < 4; reg++){
    int m = m_w + q*4 + reg;
    float2 af = ss2[m];
    float x0 = fmaxf(0.f, fmaf(acc[0][reg], af.x, af.y));
    float x1 = fmaxf(0.f, fmaf(acc[1][reg], af.x, af.y));
    float x2 = fmaxf(0.f, fmaf(acc[2][reg], af.x, af.y));
    float x3 = fmaxf(0.f, fmaf(acc[3][reg], af.x, af.y));
    float v0 = row_max16(fmaxf(x0, x1));   // query qid0   (p 0..31 of block)
    float v1 = row_max16(fmaxf(x2, x3));   // query qid0+1 (p 32..63)
    if (c == 15){
      int qa = qid0, qb = qid0 + 1;
      out1[((size_t)(qa >> 10) << 18) + (size_t)m*1024 + (qa & 1023)] = v0;
      out1[((size_t)(qb >> 10) << 18) + (size_t)m*1024 + (qb & 1023)] = v1;
    }
  }
}

__global__ __launch_bounds__(256) void k_stats_conv(const double* __restrict__ cpart,
                                                    const float* __restrict__ g, const float* __restrict__ bt,
                                                    float2* __restrict__ ssv){
  __shared__ double rs_[256], rq_[256];
  int ch = blockIdx.x, t = threadIdx.x;
  double s = 0.0, q = 0.0;
  for (int i = t; i < 2048; i += 256){ s += cpart[((size_t)ch*2048 + i)*2]; q += cpart[((size_t)ch*2048 + i)*2+1]; }
  rs_[t] = s; rq_[t] = q; __syncthreads();
  for (int off = 128; off; off >>= 1){
    if (t < off){ rs_[t] += rs_[t+off]; rq_[t] += rq_[t+off]; }
    __syncthreads();
  }
  if (t == 0){
    double cnt = (double)PP;
    double mu = rs_[0]/cnt; double var = rq_[0]/cnt - mu*mu;
    float rsf = 1.0f / sqrtf((float)var + 1e-5f);
    double rsd = (double)rsf;
    double gd = (double)g[ch]; double bd = (double)bt[ch];
    ssv[ch] = make_float2((float)(rsd*gd), (float)(bd - mu*rsd*gd));
  }
}

// ---------- elementwise BN affine + relu, in place on K8-packed bf16 (16 kgroups) ----------
__global__ __launch_bounds__(256) void k_affine(u16* __restrict__ y, const float2* __restrict__ aff){
  int tid = blockIdx.x*256 + threadIdx.x;
  int kg = tid >> 17; int p = tid & (PP - 1);
  uint4* ptr = (uint4*)(y + (((size_t)kg*PP) + p)*8);
  uint4 u = *ptr;
  u32 us[4] = {u.x, u.y, u.z, u.w};
  u32 outp[4];
  #pragma unroll
  for (int i = 0; i < 4; i++){
    float2 a0 = aff[kg*8 + 2*i], a1 = aff[kg*8 + 2*i + 1];
    float v0 = fmaxf(0.f, fmaf(bf2f(us[i] & 0xFFFFu), a0.x, a0.y));
    float v1 = fmaxf(0.f, fmaf(bf2f(us[i] >> 16),     a1.x, a1.y));
    outp[i] = (u32)f2bf(v0) | ((u32)f2bf(v1) << 16);
  }
  *ptr = make_uint4(outp[0], outp[1], outp[2], outp[3]);
}

extern "C" void kernel_launch(void* const* d_in, const int* in_sizes, int n_in,
                              void* d_out, int out_size, void* d_ws, size_t ws_size,
                              hipStream_t stream){
  (void)in_sizes; (void)n_in; (void)out_size;
  if (ws_size < WS_NEED) return;
  const float* xyz    = (const float*)d_in[0];
  const float* feat   = (const float*)d_in[1];
  const float* w1     = (const float*)d_in[2];
  const float* g1     = (const float*)d_in[3];
  const float* b1     = (const float*)d_in[4];
  const float* w2     = (const float*)d_in[5];
  const float* g2     = (const float*)d_in[6];
  const float* b2     = (const float*)d_in[7];
  const float* w3     = (const float*)d_in[8];
  const float* g3     = (const float*)d_in[9];
  const float* b3     = (const float*)d_in[10];
  const float* fw1    = (const float*)d_in[11];
  const float* fg1    = (const float*)d_in[12];
  const float* fb1    = (const float*)d_in[13];
  const float* fw2    = (const float*)d_in[14];
  const float* fbias2 = (const float*)d_in[15];

  char* ws = (char*)d_ws;
  float*  newxyz = (float*)(ws + OFF_NEWXYZ);
  float*  margin = (float*)(ws + OFF_MARGIN);
  u32*    fgmask = (u32*)(ws + OFF_FGMASK);
  int*    idxnb  = (int*)(ws + OFF_IDXNB);
  float*  mstat  = (float*)(ws + OFF_MSTAT);
  float2* ss0    = (float2*)(ws + OFF_SSA);
  float2* ss1    = ss0 + 128;
  float2* ss2    = ss0 + 256;
  float*  wt0    = (float*)(ws + OFF_WT0);
  u16*    w1b    = (u16*)(ws + OFF_W1B);
  u16*    w2b    = (u16*)(ws + OFF_W2B);
  u16*    w3b    = (u16*)(ws + OFF_W3B);
  double* mpart  = (double*)(ws + OFF_MPART);
  double* cpart  = (double*)(ws + OFF_CPART);
  u16*    Y1p    = (u16*)(ws + OFF_REGB);     // 32 MB K8 bf16
  float*  y0     = (float*)(ws + OFF_REGA);
  float*  cx     = (float*)(ws + OFF_REGA);
  float*  cy     = cx + 4*16384;
  float*  cz     = cy + 4*16384;
  int*    cg     = (int*)(cz + 4*16384);
  u16*    Xb2    = (u16*)(ws + OFF_REGA);
  u16*    Y2p    = (u16*)(ws + OFF_REGA);

  float* out  = (float*)d_out;
  float* out0 = out;            // [4,1024,3]
  float* out1 = out + 12288;    // [4,256,1024]
  float* out2 = out + 1060864;  // [4,1024]
  float* out3 = out + 1064960;  // [4,2,16384]

  k_prep<<<dim3(256), dim3(256), 0, stream>>>(w1, w2, w3, fw1, wt0, w1b, w2b, w3b);
  k_gemm_mask<<<dim3(256,1,4), dim3(256), 0, stream>>>(wt0, feat, y0, mpart);
  k_mask_stats<<<dim3(1), dim3(64), 0, stream>>>(mpart, mstat);
  k_scores<<<dim3(64,4), dim3(256), 0, stream>>>(y0, mstat, fg1, fb1, fw2, fbias2, margin, out3);
  k_topk<<<dim3(4), dim3(1024), 0, stream>>>(margin, fgmask);
  k_compact<<<dim3(8), dim3(1024), 0, stream>>>(xyz, fgmask, cx, cy, cz, cg);
  k_fps<<<dim3(8), dim3(512), 0, stream>>>(cx, cy, cz, cg, newxyz, out0, out2);
  k_ball<<<dim3(1024), dim3(256), 0, stream>>>(xyz, newxyz, idxnb);
  k_buildX<<<dim3(512), dim3(256), 0, stream>>>(xyz, newxyz, idxnb, feat, Xb2);
  k_mfma<5,1><<<dim3(2048,2), dim3(256), 0, stream>>>(w1b, 160, Xb2, Y1p, cpart);
  k_stats_conv<<<dim3(128), dim3(256), 0, stream>>>(cpart, g1, b1, ss0);
  k_affine<<<dim3(8192), dim3(256), 0, stream>>>(Y1p, ss0);
  k_mfma<4,1><<<dim3(2048,2), dim3(256), 0, stream>>>(w2b, 128, Y1p, Y2p, cpart);
  k_stats_conv<<<dim3(128), dim3(256), 0, stream>>>(cpart, g2, b2, ss1);
  k_affine<<<dim3(8192), dim3(256), 0, stream>>>(Y2p, ss1);
  k_mfma<4,0><<<dim3(2048,4), dim3(256), 0, stream>>>(w3b, 128, Y2p, (u16*)nullptr, cpart);
  k_stats_conv<<<dim3(256), dim3(256), 0, stream>>>(cpart, g3, b3, ss2);
  k_mfma_pool<<<dim3(2048,4), dim3(256), 0, stream>>>(w3b, Y2p, ss2, out1);
}

// Round 11
// 1168.825 us; speedup vs baseline: 1.2451x; 1.0548x over previous
//
#include <hip/hip_runtime.h>

#define BB 4
#define NPT 16384
#define CIN 128
#define SS 1024
#define NS 32
#define PP 131072   // BB*SS*NS
#define TOPKK 2048

typedef unsigned short u16;
typedef unsigned int u32;
typedef unsigned long long u64;
typedef float v2 __attribute__((ext_vector_type(2)));
typedef short bf16x8 __attribute__((ext_vector_type(8)));
typedef float f32x4 __attribute__((ext_vector_type(4)));

// ---------- helpers ----------
__device__ __forceinline__ float bf2f(u32 v){ return __uint_as_float(v << 16); }
__device__ __forceinline__ u16 f2bf(float f){
  u32 u = __float_as_uint(f);
  u32 r = (u + 0x7FFFu + ((u >> 16) & 1u)) >> 16;   // RNE
  return (u16)r;
}
__device__ __forceinline__ u32 keyOf(float m){
  u32 u = __float_as_uint(m);
  return (u & 0x80000000u) ? ~u : (u | 0x80000000u);  // monotone in float order
}

// f32 max over each 16-lane row (lane c=15 of the row holds the result). values >= 0.
__device__ __forceinline__ float row_max16(float v){
  #define STEP(CTRL) { int o_ = __builtin_amdgcn_update_dpp(0, __float_as_int(v), CTRL, 0xf, 0xf, true); \
                       v = fmaxf(v, __int_as_float(o_)); }
  STEP(0x111) STEP(0x112) STEP(0x114) STEP(0x118)
  #undef STEP
  return v;
}

// ---------- ws layout (bytes) — total 86,342,144 (82.3 MB) ----------
#define OFF_NEWXYZ 0ull                 // B*S*3 f32        49152
#define OFF_MARGIN 49152ull             // B*N f32          262144
#define OFF_FGMASK 311296ull            // B*N u32          262144
#define OFF_IDXNB  573440ull            // B*S*NS i32       524288
#define OFF_MSTAT  1097728ull           // 64*2 f32         512
#define OFF_SSA    1098240ull           // 512 float2       6144 (ss0:128, ss1:128, ss2:256)
#define OFF_WT0    1104384ull           // 128*64 f32       32768
#define OFF_W1B    1137152ull           // 128*160 bf16     40960
#define OFF_W2B    1178112ull           // 128*128 bf16     32768
#define OFF_W3B    1210880ull           // 256*128 bf16     65536
#define OFF_MPART  1407488ull           // 64*1024*2 f64    1048576
#define OFF_CPART  2456064ull           // 256*2048*2 f64   8388608
#define OFF_REGB   10844672ull          // featT2 (21MB bf16, dead after buildX) then Y1p (32MB K8)
#define OFF_REGA   44399104ull          // y0(16MB) -> cxyz(1MB) -> Xb2(40MB K8) -> Y2p(32MB K8)
#define WS_NEED    86342144ull

// ---------- prep: weights (fp32 mask-head; bf16 [M][Kpad] for MFMA) ----------
__global__ void k_prep(const float* __restrict__ w1, const float* __restrict__ w2,
                       const float* __restrict__ w3, const float* __restrict__ fw1,
                       float* __restrict__ wt0, u16* __restrict__ w1b, u16* __restrict__ w2b,
                       u16* __restrict__ w3b){
  int gt = blockIdx.x*blockDim.x + threadIdx.x;
  int gs = gridDim.x*blockDim.x;
  for (int i = gt; i < 128*64;  i += gs){ int k=i>>6, m=i&63;  wt0[i] = fw1[m*128+k]; }
  for (int i = gt; i < 128*160; i += gs){ int m=i/160, k=i-m*160; w1b[i] = (k<131)? f2bf(w1[m*131+k]) : (u16)0; }
  for (int i = gt; i < 128*128; i += gs){ w2b[i] = f2bf(w2[i]); }
  for (int i = gt; i < 256*128; i += gs){ w3b[i] = f2bf(w3[i]); }
}

// ---------- feat transpose: featT2[b][n][160] bf16, channel c stored at slot c+3, pads zero ----------
__global__ __launch_bounds__(256) void k_prepT(const float* __restrict__ feat, u16* __restrict__ featT2){
  __shared__ u16 tile[128][66];
  int b = blockIdx.y; int n0 = blockIdx.x * 64;
  int t = threadIdx.x;
  #pragma unroll
  for (int it = 0; it < 32; it++){
    int idx = it*256 + t; int c = idx >> 6, nn = idx & 63;
    tile[c][nn] = f2bf(feat[((size_t)b*CIN + c)*NPT + n0 + nn]);
  }
  __syncthreads();
  for (int it = 0; it < 40; it++){
    int idx = it*256 + t; int nn = idx / 160; int c = idx - nn*160;
    u16 v = (c >= 3 && c < 131) ? tile[c-3][nn] : (u16)0;
    featT2[((size_t)(b*NPT + n0 + nn))*160 + c] = v;
  }
}

// ---------- mask-head GEMM (fp32 exact path): y0[b][64][N] + deterministic stat partials ----------
__global__ __launch_bounds__(256) void k_gemm_mask(const float* __restrict__ Wt,    // [128][64]
                                                   const float* __restrict__ feat,  // [B][128][N] f32
                                                   float* __restrict__ y0,
                                                   double* __restrict__ mpart){     // [64][1024][2]
  __shared__ float As[32][64];
  __shared__ float Bs[32][64];
  int t = threadIdx.x, tx = t & 15, ty = t >> 4;
  int p0 = blockIdx.x * 64; int b = blockIdx.z;
  const float* X = feat + (size_t)b * CIN * NPT;
  float acc[4][4] = {};
  int e = t * 8, ka = e >> 6, ca = e & 63;
  for (int kc = 0; kc < 4; kc++){
    const float* wr = Wt + (size_t)(kc*32 + ka) * 64 + ca;
    float4 w0 = *(const float4*)wr;
    float4 w1v = *(const float4*)(wr + 4);
    const float* br = X + (size_t)(kc*32 + ka) * NPT + p0 + ca;
    float4 b0 = *(const float4*)br;
    float4 b1 = *(const float4*)(br + 4);
    __syncthreads();
    *(float4*)&As[ka][ca] = w0; *(float4*)&As[ka][ca+4] = w1v;
    *(float4*)&Bs[ka][ca] = b0; *(float4*)&Bs[ka][ca+4] = b1;
    __syncthreads();
    #pragma unroll
    for (int k = 0; k < 32; k++){
      float4 a = *(float4*)&As[k][ty*4];
      float4 bq = *(float4*)&Bs[k][tx*4];
      float av[4] = {a.x,a.y,a.z,a.w}; float bw[4] = {bq.x,bq.y,bq.z,bq.w};
      #pragma unroll
      for (int i = 0; i < 4; i++)
        #pragma unroll
        for (int j = 0; j < 4; j++) acc[i][j] = fmaf(av[i], bw[j], acc[i][j]);
    }
  }
  #pragma unroll
  for (int i = 0; i < 4; i++){
    int m = ty*4 + i;
    float4 v = make_float4(acc[i][0], acc[i][1], acc[i][2], acc[i][3]);
    *(float4*)(y0 + ((size_t)(b*64 + m)) * NPT + p0 + tx*4) = v;
  }
  __syncthreads();
  float* red = (float*)As;
  #pragma unroll
  for (int i = 0; i < 4; i++){
    float s = 0.f, q = 0.f;
    #pragma unroll
    for (int j = 0; j < 4; j++){ s += acc[i][j]; q += acc[i][j]*acc[i][j]; }
    red[((ty*4+i)*16 + tx)*2] = s; red[((ty*4+i)*16 + tx)*2 + 1] = q;
  }
  __syncthreads();
  if (t < 64){
    double s = 0.0, q = 0.0;
    for (int x = 0; x < 16; x++){ s += red[(t*16+x)*2]; q += red[(t*16+x)*2+1]; }
    int slot = b*256 + blockIdx.x;
    mpart[((size_t)t*1024 + slot)*2] = s;
    mpart[((size_t)t*1024 + slot)*2 + 1] = q;
  }
}

__global__ void k_mask_stats(const double* __restrict__ mpart, float* __restrict__ mstat){ // <<<1,64>>>
  int t = threadIdx.x;
  double s = 0.0, q = 0.0;
  for (int i = 0; i < 1024; i++){ s += mpart[((size_t)t*1024 + i)*2]; q += mpart[((size_t)t*1024 + i)*2+1]; }
  double cnt = 65536.0;
  double mu = s/cnt; double var = q/cnt - mu*mu;
  mstat[t*2] = (float)mu; mstat[t*2+1] = 1.0f / sqrtf((float)var + 1e-5f);
}

// ---------- scores + margin ----------
__global__ __launch_bounds__(256) void k_scores(const float* __restrict__ y0, const float* __restrict__ mstat,
                                                const float* __restrict__ fg1, const float* __restrict__ fb1,
                                                const float* __restrict__ fw2, const float* __restrict__ fbias2,
                                                float* __restrict__ margin, float* __restrict__ out3){
  __shared__ float smu[64], srs[64], sg[64], sb[64], sw[128];
  int t = threadIdx.x; int b = blockIdx.y; int n = blockIdx.x*256 + t;
  if (t < 64){ smu[t] = mstat[t*2]; srs[t] = mstat[t*2+1]; sg[t] = fg1[t]; sb[t] = fb1[t]; }
  if (t < 128) sw[t] = fw2[t];
  __syncthreads();
  float a0 = 0.f, a1 = 0.f;
  const float* yb = y0 + (size_t)b*64*NPT + n;
  for (int o = 0; o < 64; o++){
    float y = yb[(size_t)o * NPT];
    float h = __fmul_rn(__fmul_rn(__fsub_rn(y, smu[o]), srs[o]), sg[o]);
    h = __fadd_rn(h, sb[o]);
    h = fmaxf(h, 0.f);
    a0 = fmaf(sw[o], h, a0);
    a1 = fmaf(sw[64+o], h, a1);
  }
  float s0 = __fadd_rn(a0, fbias2[0]);
  float s1 = __fadd_rn(a1, fbias2[1]);
  out3[(size_t)(b*2)*NPT + n] = s0;
  out3[(size_t)(b*2+1)*NPT + n] = s1;
  float m = fmaxf(s0, s1);
  float e0 = expf(__fsub_rn(s0, m));
  float e1 = expf(__fsub_rn(s1, m));
  float den = __fadd_rn(e0, e1);
  margin[b*NPT + n] = __fsub_rn(__fdiv_rn(e1, den), __fdiv_rn(e0, den));
}

// ---------- top-2048 per batch -> fg mask (radix select + ballot-scan flag phase) ----------
__global__ __launch_bounds__(1024) void k_topk(const float* __restrict__ margin, u32* __restrict__ fgmask){
  int t = threadIdx.x; int b = blockIdx.x;
  int lane = t & 63, wv = t >> 6;
  const float* mg = margin + b*NPT; u32* fm = fgmask + b*NPT;
  __shared__ int hist[256];
  __shared__ int swt[2][16];
  __shared__ u32 s_bin; __shared__ int s_need;
  int need = TOPKK; u32 prefix = 0, kmask = 0;
  for (int r = 0; r < 4; r++){
    int shift = 24 - 8*r;
    if (t < 256) hist[t] = 0;
    __syncthreads();
    for (int j = 0; j < 16; j++){
      u32 key = keyOf(mg[j*1024 + t]);
      if ((key & kmask) == prefix) atomicAdd(&hist[(key >> shift) & 255], 1);
    }
    __syncthreads();
    if (t == 0){
      int cum = 0;
      for (int bin = 255; bin >= 0; bin--){
        int c = hist[bin];
        if (cum + c >= need){ s_bin = (u32)bin; s_need = need - cum; break; }
        cum += c;
      }
    }
    __syncthreads();
    prefix |= s_bin << shift; kmask |= 255u << shift; need = s_need;
    __syncthreads();
  }
  u32 T = prefix;
  int run = 0;
  for (int j = 0; j < 16; j++){
    int n = j*1024 + t;
    u32 key = keyOf(mg[n]);
    int eq = (key == T) ? 1 : 0;
    int gt = (key > T) ? 1 : 0;
    u64 bal = __ballot(eq != 0);
    int lexcl = __popcll(bal & ((1ull << lane) - 1ull));
    if (lane == 0) swt[j & 1][wv] = __popcll(bal);
    __syncthreads();
    int base = 0, tot = 0;
    #pragma unroll
    for (int w = 0; w < 16; w++){
      int c = swt[j & 1][w];
      tot += c;
      if (w < wv) base += c;
    }
    int flag = gt | (eq & ((run + base + lexcl) < need ? 1 : 0));
    fm[n] = (u32)flag;
    run += tot;
  }
}

// ---------- compact masked candidates (stable, ascending index) ----------
__global__ __launch_bounds__(1024) void k_compact(const float* __restrict__ xyz, const u32* __restrict__ fgmask,
                                                  float* __restrict__ cx, float* __restrict__ cy,
                                                  float* __restrict__ cz, int* __restrict__ cg){
  int blk = blockIdx.x; int b = blk >> 1; int which = blk & 1;
  const float* xb = xyz + (size_t)b * NPT * 3;
  const u32* mb = fgmask + b*NPT;
  int t = threadIdx.x;
  __shared__ int sc[1024];
  u32 mloc = 0; int cnt = 0;
  int p0 = t*16;
  #pragma unroll
  for (int j = 0; j < 16; j++){
    u32 m = mb[p0+j];
    bool inc = which ? (m == 0u) : (m != 0u);
    mloc |= (inc ? 1u : 0u) << j; cnt += inc ? 1 : 0;
  }
  sc[t] = cnt; __syncthreads();
  for (int off = 1; off < 1024; off <<= 1){
    int v = (t >= off) ? sc[t-off] : 0;
    __syncthreads();
    sc[t] += v;
    __syncthreads();
  }
  int pos = sc[t] - cnt;
  int base = b*16384 + (which ? 2048 : 0);
  for (int j = 0; j < 16; j++){
    if ((mloc >> j) & 1u){
      int p = p0 + j;
      cx[base+pos] = xb[p*3]; cy[base+pos] = xb[p*3+1]; cz[base+pos] = xb[p*3+2];
      cg[base+pos] = p; pos++;
    }
  }
}

// ---------- masked FPS (512 threads) — r7 reduction: all-lane atomicMax over 8 LDS slots ----------
// Iteration-prefix keys (stale entries always lose, no resets); parity double-buffer,
// single barrier per iteration. Exact lowest-index tie-break via key low bits.
// NOTE (r10 post-mortem): DPP pre-reduce before the atomic is a REGRESSION — the
// serial DPP chain adds dependent latency while atomic contention is absorbed off
// the critical path. Keep the dumb all-lane atomic.
template<int NV>   // v2-rows per thread; candidates = NV*1024 (512 threads)
__device__ __forceinline__ void fps_run(const float* __restrict__ cx, const float* __restrict__ cy,
                                        const float* __restrict__ cz, const int* __restrict__ cg,
                                        int b, int which,
                                        float* __restrict__ newxyz, float* __restrict__ out0,
                                        float* __restrict__ out2){
  #pragma clang fp contract(off)
  int t = threadIdx.x;
  __shared__ u64 slots[2][8];
  if (t < 16) ((u64*)slots)[t] = 0ull;
  v2 px[NV], py[NV], pz[NV], mind[NV];
  #pragma unroll
  for (int r = 0; r < NV; r++){
    int p0 = 1024*r + t, p1 = 1024*r + 512 + t;
    px[r].x = cx[p0]; px[r].y = cx[p1];
    py[r].x = cy[p0]; py[r].y = cy[p1];
    pz[r].x = cz[p0]; pz[r].y = cz[p1];
    mind[r].x = 1e10f; mind[r].y = 1e10f;
  }
  __syncthreads();
  float bv = 1e10f; int bi = t;   // all equal -> lowest local index
  for (int it = 0; it < 512; it++){
    u64 key = ((u64)(it+1) << 46) | ((u64)keyOf(bv) << 14) | (u64)(16383 - bi);
    atomicMax((unsigned long long*)&slots[it & 1][t & 7], (unsigned long long)key);
    __syncthreads();
    u64 k0 = slots[it & 1][0];
    #pragma unroll
    for (int i = 1; i < 8; i++){ u64 ki = slots[it & 1][i]; if (ki > k0) k0 = ki; }
    int sel = 16383 - (int)(k0 & 0x3FFFu);
    float xs = cx[sel], ys = cy[sel], zs = cz[sel];   // uniform L2-resident load
    if (t == 0){
      int s = which*512 + it;
      out2[b*1024 + s] = (float)cg[sel];
      newxyz[(b*1024 + s)*3]   = xs;
      newxyz[(b*1024 + s)*3+1] = ys;
      newxyz[(b*1024 + s)*3+2] = zs;
      out0[(b*1024 + s)*3]   = xs;
      out0[(b*1024 + s)*3+1] = ys;
      out0[(b*1024 + s)*3+2] = zs;
    }
    v2 xs2; xs2.x = xs; xs2.y = xs;
    v2 ys2; ys2.x = ys; ys2.y = ys;
    v2 zs2; zs2.x = zs; zs2.y = zs;
    bv = -1.0f; bi = 16383;
    #pragma unroll
    for (int r = 0; r < NV; r++){
      v2 dx = px[r] - xs2;
      v2 dy = py[r] - ys2;
      v2 dz = pz[r] - zs2;
      v2 qx = dx * dx;
      v2 qy = dy * dy;
      v2 qz = dz * dz;
      v2 s1 = qx + qy;
      v2 d  = s1 + qz;
      float m0 = fminf(mind[r].x, d.x);
      float m1 = fminf(mind[r].y, d.y);
      mind[r].x = m0; mind[r].y = m1;
      if (m0 > bv){ bv = m0; bi = 1024*r + t; }
      if (m1 > bv){ bv = m1; bi = 1024*r + 512 + t; }
    }
  }
}

__global__ __launch_bounds__(512) void k_fps(const float* __restrict__ cx, const float* __restrict__ cy,
                                             const float* __restrict__ cz, const int* __restrict__ cg,
                                             float* __restrict__ newxyz, float* __restrict__ out0,
                                             float* __restrict__ out2){
  int b = blockIdx.x >> 1; int which = blockIdx.x & 1;
  int base = b*16384 + (which ? 2048 : 0);
  if (which) fps_run<14>(cx+base, cy+base, cz+base, cg+base, b, 1, newxyz, out0, out2);
  else       fps_run<2 >(cx+base, cy+base, cz+base, cg+base, b, 0, newxyz, out0, out2);
}

// ---------- ball query: one wave per query (inclusive <=, f32 radius^2) ----------
__global__ __launch_bounds__(256) void k_ball(const float* __restrict__ xyz, const float* __restrict__ newxyz,
                                              int* __restrict__ idxnb){
  int t = threadIdx.x; int lane = t & 63;
  int qid = blockIdx.x*4 + (t >> 6);
  int b = qid >> 10;
  const float* xb = xyz + (size_t)b * NPT * 3;
  float qx = newxyz[qid*3], qy = newxyz[qid*3+1], qz = newxyz[qid*3+2];
  int found = 0, first = -1;
  for (int base = 0; base < NPT; base += 64){
    int p = base + lane;
    float x = xb[p*3], y = xb[p*3+1], z = xb[p*3+2];
    float dx = __fsub_rn(qx, x), dy = __fsub_rn(qy, y), dz = __fsub_rn(qz, z);
    float d2 = __fadd_rn(__fadd_rn(__fmul_rn(dx,dx), __fmul_rn(dy,dy)), __fmul_rn(dz,dz));
    bool w = d2 <= 0.09f;
    u64 m = __ballot(w);
    if (first < 0 && m) first = base + __ffsll((unsigned long long)m) - 1;
    if (w){
      int pos = found + __popcll(m & ((1ull << lane) - 1ull));
      if (pos < NS) idxnb[(size_t)qid*NS + pos] = p;
    }
    found += __popcll(m);
    if (found >= NS) break;
  }
  if (first < 0) first = 0;
  if (lane < NS && lane >= found) idxnb[(size_t)qid*NS + lane] = first;
}

// ---------- build grouped input Xb2 [kg][P][8] bf16 from transposed featT2 rows ----------
__global__ __launch_bounds__(256) void k_buildX(const float* __restrict__ xyz, const float* __restrict__ newxyz,
                                                const int* __restrict__ idxnb, const u16* __restrict__ featT2,
                                                u16* __restrict__ Xb2){
  int pos = blockIdx.x*256 + threadIdx.x;
  int b = pos >> 15; int r = pos & 32767; int s = r >> 5;
  int gi = idxnb[pos] & (NPT - 1);
  const float* xp = xyz + ((size_t)b*NPT + gi) * 3;
  const float* qp = newxyz + ((size_t)(b << 10) + s) * 3;
  u16 d0 = f2bf(__fsub_rn(xp[0], qp[0]));
  u16 d1 = f2bf(__fsub_rn(xp[1], qp[1]));
  u16 d2 = f2bf(__fsub_rn(xp[2], qp[2]));
  const uint4* row = (const uint4*)(featT2 + (size_t)(b*NPT + gi) * 160);
  #pragma unroll
  for (int kg = 0; kg < 20; kg++){
    uint4 u = row[kg];
    if (kg == 0){
      u.x = (u32)d0 | ((u32)d1 << 16);
      u.y = (u.y & 0xFFFF0000u) | (u32)d2;
    }
    *(uint4*)(Xb2 + ((size_t)kg*PP + pos)*8) = u;
  }
}

// ---------- MFMA conv layer: Y[M][P] = Wb[M][Kpad] x Xp(K8) ; K8-packed bf16 out + f64 stat partials ----------
template<int NKS, int STORE>
__global__ __launch_bounds__(256) void k_mfma(const u16* __restrict__ Wb, int Kpad,
                                              const u16* __restrict__ Xp,
                                              u16* __restrict__ Yp, double* __restrict__ cpart){
  __shared__ float sred[4][16][16][2];
  int t = threadIdx.x;
  int w = t >> 6, lane = t & 63;
  int q = lane >> 4, c = lane & 15;
  int p0 = blockIdx.x * 64, m0 = blockIdx.y * 64;
  int m_w = m0 + w*16;
  f32x4 acc[4] = {{0.f,0.f,0.f,0.f},{0.f,0.f,0.f,0.f},{0.f,0.f,0.f,0.f},{0.f,0.f,0.f,0.f}};
  const u16* arow = Wb + (size_t)(m_w + c) * Kpad + q*8;
  #pragma unroll
  for (int ks = 0; ks < NKS; ks++){
    bf16x8 afrag = *(const bf16x8*)(arow + ks*32);
    #pragma unroll
    for (int pp = 0; pp < 4; pp++){
      int p = p0 + pp*16 + c;
      bf16x8 bfrag = *(const bf16x8*)(Xp + (((size_t)(ks*4 + q) * PP) + p) * 8);
      acc[pp] = __builtin_amdgcn_mfma_f32_16x16x32_bf16(afrag, bfrag, acc[pp], 0, 0, 0);
    }
  }
  #pragma unroll
  for (int reg = 0; reg < 4; reg++){
    float s = 0.f, sq = 0.f;
    #pragma unroll
    for (int pp = 0; pp < 4; pp++){ float v = acc[pp][reg]; s += v; sq += v*v; }
    sred[w][q*4+reg][c][0] = s; sred[w][q*4+reg][c][1] = sq;
  }
  if (STORE){
    int kgm = (m_w + q*4) >> 3;
    int j0 = (m_w + q*4) & 7;
    #pragma unroll
    for (int pp = 0; pp < 4; pp++){
      int p = p0 + pp*16 + c;
      ushort4 pk;
      pk.x = f2bf(acc[pp][0]); pk.y = f2bf(acc[pp][1]); pk.z = f2bf(acc[pp][2]); pk.w = f2bf(acc[pp][3]);
      *(ushort4*)(Yp + (((size_t)kgm * PP) + p) * 8 + j0) = pk;
    }
  }
  __syncthreads();
  if (t < 64){
    int ww = t >> 4, ml = t & 15;
    double s = 0.0, qq = 0.0;
    for (int cc = 0; cc < 16; cc++){ s += sred[ww][ml][cc][0]; qq += sred[ww][ml][cc][1]; }
    cpart[((size_t)(m0 + t) * 2048 + blockIdx.x)*2] = s;
    cpart[((size_t)(m0 + t) * 2048 + blockIdx.x)*2 + 1] = qq;
  }
}

// ---------- layer-3 recompute via MFMA + BN3 affine + relu + maxpool epilogue (no Y3 store) ----------
__global__ __launch_bounds__(256) void k_mfma_pool(const u16* __restrict__ Wb,       // w3b [256][128]
                                                   const u16* __restrict__ Xp,       // affined Y2 (K8)
                                                   const float2* __restrict__ ss2,
                                                   float* __restrict__ out1){
  int t = threadIdx.x;
  int w = t >> 6, lane = t & 63;
  int q = lane >> 4, c = lane & 15;
  int p0 = blockIdx.x * 64, m0 = blockIdx.y * 64;
  int m_w = m0 + w*16;
  f32x4 acc[4] = {{0.f,0.f,0.f,0.f},{0.f,0.f,0.f,0.f},{0.f,0.f,0.f,0.f},{0.f,0.f,0.f,0.f}};
  const u16* arow = Wb + (size_t)(m_w + c) * 128 + q*8;
  #pragma unroll
  for (int ks = 0; ks < 4; ks++){
    bf16x8 afrag = *(const bf16x8*)(arow + ks*32);
    #pragma unroll
    for (int pp = 0; pp < 4; pp++){
      int p = p0 + pp*16 + c;
      bf16x8 bfrag = *(const bf16x8*)(Xp + (((size_t)(ks*4 + q) * PP) + p) * 8);
      acc[pp] = __builtin_amdgcn_mfma_f32_16x16x32_bf16(afrag, bfrag, acc[pp], 0, 0, 0);
    }
  }
  int qid0 = blockIdx.x*2;
  #pragma unroll
  for (int reg = 0; reg < 4; reg++){
    int m = m_w + q*4 + reg;
    float2 af = ss2[m];
    float x0 = fmaxf(0.f, fmaf(acc[0][reg], af.x, af.y));
    float x1 = fmaxf(0.f, fmaf(acc[1][reg], af.x, af.y));
    float x2 = fmaxf(0.f, fmaf(acc[2][reg], af.x, af.y));
    float x3 = fmaxf(0.f, fmaf(acc[3][reg], af.x, af.y));
    float v0 = row_max16(fmaxf(x0, x1));   // query qid0   (p 0..31 of block)
    float v1 = row_max16(fmaxf(x2, x3));   // query qid0+1 (p 32..63)
    if (c == 15){
      int qa = qid0, qb = qid0 + 1;
      out1[((size_t)(qa >> 10) << 18) + (size_t)m*1024 + (qa & 1023)] = v0;
      out1[((size_t)(qb >> 10) << 18) + (size_t)m*1024 + (qb & 1023)] = v1;
    }
  }
}

__global__ __launch_bounds__(256) void k_stats_conv(const double* __restrict__ cpart,
                                                    const float* __restrict__ g, const float* __restrict__ bt,
                                                    float2* __restrict__ ssv){
  __shared__ double rs_[256], rq_[256];
  int ch = blockIdx.x, t = threadIdx.x;
  double s = 0.0, q = 0.0;
  for (int i = t; i < 2048; i += 256){ s += cpart[((size_t)ch*2048 + i)*2]; q += cpart[((size_t)ch*2048 + i)*2+1]; }
  rs_[t] = s; rq_[t] = q; __syncthreads();
  for (int off = 128; off; off >>= 1){
    if (t < off){ rs_[t] += rs_[t+off]; rq_[t] += rq_[t+off]; }
    __syncthreads();
  }
  if (t == 0){
    double cnt = (double)PP;
    double mu = rs_[0]/cnt; double var = rq_[0]/cnt - mu*mu;
    float rsf = 1.0f / sqrtf((float)var + 1e-5f);
    double rsd = (double)rsf;
    double gd = (double)g[ch]; double bd = (double)bt[ch];
    ssv[ch] = make_float2((float)(rsd*gd), (float)(bd - mu*rsd*gd));
  }
}

// ---------- elementwise BN affine + relu, in place on K8-packed bf16 (16 kgroups) ----------
__global__ __launch_bounds__(256) void k_affine(u16* __restrict__ y, const float2* __restrict__ aff){
  int tid = blockIdx.x*256 + threadIdx.x;
  int kg = tid >> 17; int p = tid & (PP - 1);
  uint4* ptr = (uint4*)(y + (((size_t)kg*PP) + p)*8);
  uint4 u = *ptr;
  u32 us[4] = {u.x, u.y, u.z, u.w};
  u32 outp[4];
  #pragma unroll
  for (int i = 0; i < 4; i++){
    float2 a0 = aff[kg*8 + 2*i], a1 = aff[kg*8 + 2*i + 1];
    float v0 = fmaxf(0.f, fmaf(bf2f(us[i] & 0xFFFFu), a0.x, a0.y));
    float v1 = fmaxf(0.f, fmaf(bf2f(us[i] >> 16),     a1.x, a1.y));
    outp[i] = (u32)f2bf(v0) | ((u32)f2bf(v1) << 16);
  }
  *ptr = make_uint4(outp[0], outp[1], outp[2], outp[3]);
}

extern "C" void kernel_launch(void* const* d_in, const int* in_sizes, int n_in,
                              void* d_out, int out_size, void* d_ws, size_t ws_size,
                              hipStream_t stream){
  (void)in_sizes; (void)n_in; (void)out_size;
  if (ws_size < WS_NEED) return;
  const float* xyz    = (const float*)d_in[0];
  const float* feat   = (const float*)d_in[1];
  const float* w1     = (const float*)d_in[2];
  const float* g1     = (const float*)d_in[3];
  const float* b1     = (const float*)d_in[4];
  const float* w2     = (const float*)d_in[5];
  const float* g2     = (const float*)d_in[6];
  const float* b2     = (const float*)d_in[7];
  const float* w3     = (const float*)d_in[8];
  const float* g3     = (const float*)d_in[9];
  const float* b3     = (const float*)d_in[10];
  const float* fw1    = (const float*)d_in[11];
  const float* fg1    = (const float*)d_in[12];
  const float* fb1    = (const float*)d_in[13];
  const float* fw2    = (const float*)d_in[14];
  const float* fbias2 = (const float*)d_in[15];

  char* ws = (char*)d_ws;
  float*  newxyz = (float*)(ws + OFF_NEWXYZ);
  float*  margin = (float*)(ws + OFF_MARGIN);
  u32*    fgmask = (u32*)(ws + OFF_FGMASK);
  int*    idxnb  = (int*)(ws + OFF_IDXNB);
  float*  mstat  = (float*)(ws + OFF_MSTAT);
  float2* ss0    = (float2*)(ws + OFF_SSA);
  float2* ss1    = ss0 + 128;
  float2* ss2    = ss0 + 256;
  float*  wt0    = (float*)(ws + OFF_WT0);
  u16*    w1b    = (u16*)(ws + OFF_W1B);
  u16*    w2b    = (u16*)(ws + OFF_W2B);
  u16*    w3b    = (u16*)(ws + OFF_W3B);
  double* mpart  = (double*)(ws + OFF_MPART);
  double* cpart  = (double*)(ws + OFF_CPART);
  // Region B phases: featT2 (21MB, dead after k_buildX) -> Y1p (32MB K8)
  u16*    featT2 = (u16*)(ws + OFF_REGB);
  u16*    Y1p    = (u16*)(ws + OFF_REGB);
  // Region A phases: y0 (16MB f32) -> cx/cy/cz/cg (1MB) -> Xb2 (40MB K8) -> Y2p (32MB K8)
  float*  y0     = (float*)(ws + OFF_REGA);
  float*  cx     = (float*)(ws + OFF_REGA);
  float*  cy     = cx + 4*16384;
  float*  cz     = cy + 4*16384;
  int*    cg     = (int*)(cz + 4*16384);
  u16*    Xb2    = (u16*)(ws + OFF_REGA);
  u16*    Y2p    = (u16*)(ws + OFF_REGA);

  float* out  = (float*)d_out;
  float* out0 = out;            // [4,1024,3]
  float* out1 = out + 12288;    // [4,256,1024]
  float* out2 = out + 1060864;  // [4,1024]
  float* out3 = out + 1064960;  // [4,2,16384]

  k_prep<<<dim3(256), dim3(256), 0, stream>>>(w1, w2, w3, fw1, wt0, w1b, w2b, w3b);
  k_prepT<<<dim3(256,4), dim3(256), 0, stream>>>(feat, featT2);
  k_gemm_mask<<<dim3(256,1,4), dim3(256), 0, stream>>>(wt0, feat, y0, mpart);
  k_mask_stats<<<dim3(1), dim3(64), 0, stream>>>(mpart, mstat);
  k_scores<<<dim3(64,4), dim3(256), 0, stream>>>(y0, mstat, fg1, fb1, fw2, fbias2, margin, out3);
  k_topk<<<dim3(4), dim3(1024), 0, stream>>>(margin, fgmask);
  k_compact<<<dim3(8), dim3(1024), 0, stream>>>(xyz, fgmask, cx, cy, cz, cg);
  k_fps<<<dim3(8), dim3(512), 0, stream>>>(cx, cy, cz, cg, newxyz, out0, out2);
  k_ball<<<dim3(1024), dim3(256), 0, stream>>>(xyz, newxyz, idxnb);
  k_buildX<<<dim3(512), dim3(256), 0, stream>>>(xyz, newxyz, idxnb, featT2, Xb2);
  k_mfma<5,1><<<dim3(2048,2), dim3(256), 0, stream>>>(w1b, 160, Xb2, Y1p, cpart);
  k_stats_conv<<<dim3(128), dim3(256), 0, stream>>>(cpart, g1, b1, ss0);
  k_affine<<<dim3(8192), dim3(256), 0, stream>>>(Y1p, ss0);
  k_mfma<4,1><<<dim3(2048,2), dim3(256), 0, stream>>>(w2b, 128, Y1p, Y2p, cpart);
  k_stats_conv<<<dim3(128), dim3(256), 0, stream>>>(cpart, g2, b2, ss1);
  k_affine<<<dim3(8192), dim3(256), 0, stream>>>(Y2p, ss1);
  k_mfma<4,0><<<dim3(2048,4), dim3(256), 0, stream>>>(w3b, 128, Y2p, (u16*)nullptr, cpart);
  k_stats_conv<<<dim3(256), dim3(256), 0, stream>>>(cpart, g3, b3, ss2);
  k_mfma_pool<<<dim3(2048,4), dim3(256), 0, stream>>>(w3b, Y2p, ss2, out1);
}

// Round 12
// 1145.442 us; speedup vs baseline: 1.2705x; 1.0204x over previous
//
#include <hip/hip_runtime.h>

#define BB 4
#define NPT 16384
#define CIN 128
#define SS 1024
#define NS 32
#define PP 131072   // BB*SS*NS
#define TOPKK 2048

typedef unsigned short u16;
typedef unsigned int u32;
typedef unsigned long long u64;
typedef float v2 __attribute__((ext_vector_type(2)));
typedef short bf16x8 __attribute__((ext_vector_type(8)));
typedef float f32x4 __attribute__((ext_vector_type(4)));

// ---------- helpers ----------
__device__ __forceinline__ float bf2f(u32 v){ return __uint_as_float(v << 16); }
__device__ __forceinline__ u16 f2bf(float f){
  u32 u = __float_as_uint(f);
  u32 r = (u + 0x7FFFu + ((u >> 16) & 1u)) >> 16;   // RNE
  return (u16)r;
}
__device__ __forceinline__ u32 keyOf(float m){
  u32 u = __float_as_uint(m);
  return (u & 0x80000000u) ? ~u : (u | 0x80000000u);  // monotone in float order
}

// f32 max over each 16-lane row (lane c=15 of the row holds the result). values >= 0.
__device__ __forceinline__ float row_max16(float v){
  #define STEP(CTRL) { int o_ = __builtin_amdgcn_update_dpp(0, __float_as_int(v), CTRL, 0xf, 0xf, true); \
                       v = fmaxf(v, __int_as_float(o_)); }
  STEP(0x111) STEP(0x112) STEP(0x114) STEP(0x118)
  #undef STEP
  return v;
}

// ---------- ws layout (bytes) — total 86,342,144 (82.3 MB) ----------
#define OFF_NEWXYZ 0ull                 // B*S*3 f32        49152
#define OFF_MARGIN 49152ull             // B*N f32          262144
#define OFF_FGMASK 311296ull            // B*N u32          262144
#define OFF_IDXNB  573440ull            // B*S*NS i32       524288
#define OFF_MSTAT  1097728ull           // 64*2 f32         512
#define OFF_SSA    1098240ull           // 512 float2       6144 (ss0:128, ss1:128, ss2:256)
#define OFF_WT0    1104384ull           // 128*64 f32       32768
#define OFF_W1B    1137152ull           // 128*160 bf16     40960
#define OFF_W2B    1178112ull           // 128*128 bf16     32768
#define OFF_W3B    1210880ull           // 256*128 bf16     65536
#define OFF_MPART  1407488ull           // 1024*64*2 f64    1048576 (transposed: [slot][64][2])
#define OFF_CPART  2456064ull           // 256*2048*2 f64   8388608
#define OFF_REGB   10844672ull          // featT2 (21MB bf16, dead after buildX) then Y1p (32MB K8)
#define OFF_REGA   44399104ull          // y0(16MB) -> cxyz(1MB) -> Xb2(40MB K8) -> Y2p(32MB K8)
#define WS_NEED    86342144ull

// ---------- prep: weights (fp32 mask-head; bf16 [M][Kpad] for MFMA) ----------
__global__ void k_prep(const float* __restrict__ w1, const float* __restrict__ w2,
                       const float* __restrict__ w3, const float* __restrict__ fw1,
                       float* __restrict__ wt0, u16* __restrict__ w1b, u16* __restrict__ w2b,
                       u16* __restrict__ w3b){
  int gt = blockIdx.x*blockDim.x + threadIdx.x;
  int gs = gridDim.x*blockDim.x;
  for (int i = gt; i < 128*64;  i += gs){ int k=i>>6, m=i&63;  wt0[i] = fw1[m*128+k]; }
  for (int i = gt; i < 128*160; i += gs){ int m=i/160, k=i-m*160; w1b[i] = (k<131)? f2bf(w1[m*131+k]) : (u16)0; }
  for (int i = gt; i < 128*128; i += gs){ w2b[i] = f2bf(w2[i]); }
  for (int i = gt; i < 256*128; i += gs){ w3b[i] = f2bf(w3[i]); }
}

// ---------- feat transpose: featT2[b][n][160] bf16, channel c stored at slot c+3, pads zero ----------
__global__ __launch_bounds__(256) void k_prepT(const float* __restrict__ feat, u16* __restrict__ featT2){
  __shared__ u16 tile[128][66];
  int b = blockIdx.y; int n0 = blockIdx.x * 64;
  int t = threadIdx.x;
  #pragma unroll
  for (int it = 0; it < 32; it++){
    int idx = it*256 + t; int c = idx >> 6, nn = idx & 63;
    tile[c][nn] = f2bf(feat[((size_t)b*CIN + c)*NPT + n0 + nn]);
  }
  __syncthreads();
  for (int it = 0; it < 40; it++){
    int idx = it*256 + t; int nn = idx / 160; int c = idx - nn*160;
    u16 v = (c >= 3 && c < 131) ? tile[c-3][nn] : (u16)0;
    featT2[((size_t)(b*NPT + n0 + nn))*160 + c] = v;
  }
}

// ---------- mask-head GEMM (fp32 exact path): y0[b][64][N] + deterministic stat partials ----------
// mpart layout TRANSPOSED to [slot][64][2] so the stats wave reads coalesced;
// per-channel summation ORDER unchanged (slot ascending) -> bit-identical stats.
__global__ __launch_bounds__(256) void k_gemm_mask(const float* __restrict__ Wt,    // [128][64]
                                                   const float* __restrict__ feat,  // [B][128][N] f32
                                                   float* __restrict__ y0,
                                                   double* __restrict__ mpart){     // [1024][64][2]
  __shared__ float As[32][64];
  __shared__ float Bs[32][64];
  int t = threadIdx.x, tx = t & 15, ty = t >> 4;
  int p0 = blockIdx.x * 64; int b = blockIdx.z;
  const float* X = feat + (size_t)b * CIN * NPT;
  float acc[4][4] = {};
  int e = t * 8, ka = e >> 6, ca = e & 63;
  for (int kc = 0; kc < 4; kc++){
    const float* wr = Wt + (size_t)(kc*32 + ka) * 64 + ca;
    float4 w0 = *(const float4*)wr;
    float4 w1v = *(const float4*)(wr + 4);
    const float* br = X + (size_t)(kc*32 + ka) * NPT + p0 + ca;
    float4 b0 = *(const float4*)br;
    float4 b1 = *(const float4*)(br + 4);
    __syncthreads();
    *(float4*)&As[ka][ca] = w0; *(float4*)&As[ka][ca+4] = w1v;
    *(float4*)&Bs[ka][ca] = b0; *(float4*)&Bs[ka][ca+4] = b1;
    __syncthreads();
    #pragma unroll
    for (int k = 0; k < 32; k++){
      float4 a = *(float4*)&As[k][ty*4];
      float4 bq = *(float4*)&Bs[k][tx*4];
      float av[4] = {a.x,a.y,a.z,a.w}; float bw[4] = {bq.x,bq.y,bq.z,bq.w};
      #pragma unroll
      for (int i = 0; i < 4; i++)
        #pragma unroll
        for (int j = 0; j < 4; j++) acc[i][j] = fmaf(av[i], bw[j], acc[i][j]);
    }
  }
  #pragma unroll
  for (int i = 0; i < 4; i++){
    int m = ty*4 + i;
    float4 v = make_float4(acc[i][0], acc[i][1], acc[i][2], acc[i][3]);
    *(float4*)(y0 + ((size_t)(b*64 + m)) * NPT + p0 + tx*4) = v;
  }
  __syncthreads();
  float* red = (float*)As;
  #pragma unroll
  for (int i = 0; i < 4; i++){
    float s = 0.f, q = 0.f;
    #pragma unroll
    for (int j = 0; j < 4; j++){ s += acc[i][j]; q += acc[i][j]*acc[i][j]; }
    red[((ty*4+i)*16 + tx)*2] = s; red[((ty*4+i)*16 + tx)*2 + 1] = q;
  }
  __syncthreads();
  if (t < 64){
    double s = 0.0, q = 0.0;
    for (int x = 0; x < 16; x++){ s += red[(t*16+x)*2]; q += red[(t*16+x)*2+1]; }
    int slot = b*256 + blockIdx.x;
    mpart[((size_t)slot*64 + t)*2] = s;
    mpart[((size_t)slot*64 + t)*2 + 1] = q;
  }
}

__global__ void k_mask_stats(const double* __restrict__ mpart, float* __restrict__ mstat){ // <<<1,64>>>
  int t = threadIdx.x;
  double s = 0.0, q = 0.0;
  for (int i = 0; i < 1024; i++){ s += mpart[((size_t)i*64 + t)*2]; q += mpart[((size_t)i*64 + t)*2+1]; }
  double cnt = 65536.0;
  double mu = s/cnt; double var = q/cnt - mu*mu;
  mstat[t*2] = (float)mu; mstat[t*2+1] = 1.0f / sqrtf((float)var + 1e-5f);
}

// ---------- scores + margin ----------
__global__ __launch_bounds__(256) void k_scores(const float* __restrict__ y0, const float* __restrict__ mstat,
                                                const float* __restrict__ fg1, const float* __restrict__ fb1,
                                                const float* __restrict__ fw2, const float* __restrict__ fbias2,
                                                float* __restrict__ margin, float* __restrict__ out3){
  __shared__ float smu[64], srs[64], sg[64], sb[64], sw[128];
  int t = threadIdx.x; int b = blockIdx.y; int n = blockIdx.x*256 + t;
  if (t < 64){ smu[t] = mstat[t*2]; srs[t] = mstat[t*2+1]; sg[t] = fg1[t]; sb[t] = fb1[t]; }
  if (t < 128) sw[t] = fw2[t];
  __syncthreads();
  float a0 = 0.f, a1 = 0.f;
  const float* yb = y0 + (size_t)b*64*NPT + n;
  for (int o = 0; o < 64; o++){
    float y = yb[(size_t)o * NPT];
    float h = __fmul_rn(__fmul_rn(__fsub_rn(y, smu[o]), srs[o]), sg[o]);
    h = __fadd_rn(h, sb[o]);
    h = fmaxf(h, 0.f);
    a0 = fmaf(sw[o], h, a0);
    a1 = fmaf(sw[64+o], h, a1);
  }
  float s0 = __fadd_rn(a0, fbias2[0]);
  float s1 = __fadd_rn(a1, fbias2[1]);
  out3[(size_t)(b*2)*NPT + n] = s0;
  out3[(size_t)(b*2+1)*NPT + n] = s1;
  float m = fmaxf(s0, s1);
  float e0 = expf(__fsub_rn(s0, m));
  float e1 = expf(__fsub_rn(s1, m));
  float den = __fadd_rn(e0, e1);
  margin[b*NPT + n] = __fsub_rn(__fdiv_rn(e1, den), __fdiv_rn(e0, den));
}

// ---------- top-2048 per batch -> fg mask (radix select + ballot-scan flag phase) ----------
__global__ __launch_bounds__(1024) void k_topk(const float* __restrict__ margin, u32* __restrict__ fgmask){
  int t = threadIdx.x; int b = blockIdx.x;
  int lane = t & 63, wv = t >> 6;
  const float* mg = margin + b*NPT; u32* fm = fgmask + b*NPT;
  __shared__ int hist[256];
  __shared__ int swt[2][16];
  __shared__ u32 s_bin; __shared__ int s_need;
  int need = TOPKK; u32 prefix = 0, kmask = 0;
  for (int r = 0; r < 4; r++){
    int shift = 24 - 8*r;
    if (t < 256) hist[t] = 0;
    __syncthreads();
    for (int j = 0; j < 16; j++){
      u32 key = keyOf(mg[j*1024 + t]);
      if ((key & kmask) == prefix) atomicAdd(&hist[(key >> shift) & 255], 1);
    }
    __syncthreads();
    if (t == 0){
      int cum = 0;
      for (int bin = 255; bin >= 0; bin--){
        int c = hist[bin];
        if (cum + c >= need){ s_bin = (u32)bin; s_need = need - cum; break; }
        cum += c;
      }
    }
    __syncthreads();
    prefix |= s_bin << shift; kmask |= 255u << shift; need = s_need;
    __syncthreads();
  }
  u32 T = prefix;
  int run = 0;
  for (int j = 0; j < 16; j++){
    int n = j*1024 + t;
    u32 key = keyOf(mg[n]);
    int eq = (key == T) ? 1 : 0;
    int gt = (key > T) ? 1 : 0;
    u64 bal = __ballot(eq != 0);
    int lexcl = __popcll(bal & ((1ull << lane) - 1ull));
    if (lane == 0) swt[j & 1][wv] = __popcll(bal);
    __syncthreads();
    int base = 0, tot = 0;
    #pragma unroll
    for (int w = 0; w < 16; w++){
      int c = swt[j & 1][w];
      tot += c;
      if (w < wv) base += c;
    }
    int flag = gt | (eq & ((run + base + lexcl) < need ? 1 : 0));
    fm[n] = (u32)flag;
    run += tot;
  }
}

// ---------- compact masked candidates (stable, ascending index) ----------
__global__ __launch_bounds__(1024) void k_compact(const float* __restrict__ xyz, const u32* __restrict__ fgmask,
                                                  float* __restrict__ cx, float* __restrict__ cy,
                                                  float* __restrict__ cz, int* __restrict__ cg){
  int blk = blockIdx.x; int b = blk >> 1; int which = blk & 1;
  const float* xb = xyz + (size_t)b * NPT * 3;
  const u32* mb = fgmask + b*NPT;
  int t = threadIdx.x;
  __shared__ int sc[1024];
  u32 mloc = 0; int cnt = 0;
  int p0 = t*16;
  #pragma unroll
  for (int j = 0; j < 16; j++){
    u32 m = mb[p0+j];
    bool inc = which ? (m == 0u) : (m != 0u);
    mloc |= (inc ? 1u : 0u) << j; cnt += inc ? 1 : 0;
  }
  sc[t] = cnt; __syncthreads();
  for (int off = 1; off < 1024; off <<= 1){
    int v = (t >= off) ? sc[t-off] : 0;
    __syncthreads();
    sc[t] += v;
    __syncthreads();
  }
  int pos = sc[t] - cnt;
  int base = b*16384 + (which ? 2048 : 0);
  for (int j = 0; j < 16; j++){
    if ((mloc >> j) & 1u){
      int p = p0 + j;
      cx[base+pos] = xb[p*3]; cy[base+pos] = xb[p*3+1]; cz[base+pos] = xb[p*3+2];
      cg[base+pos] = p; pos++;
    }
  }
}

// ---------- masked FPS (512 threads) — r7 reduction: all-lane atomicMax over 8 LDS slots ----------
// Iteration-prefix keys (stale entries always lose, no resets); parity double-buffer,
// single barrier per iteration. Exact lowest-index tie-break via key low bits.
// NOTE (r10/r11 A/B): DPP pre-reduce before the atomic REGRESSES — atomic contention
// drains off the critical path; keep the dumb all-lane atomic. 512thr > 1024thr.
template<int NV>   // v2-rows per thread; candidates = NV*1024 (512 threads)
__device__ __forceinline__ void fps_run(const float* __restrict__ cx, const float* __restrict__ cy,
                                        const float* __restrict__ cz, const int* __restrict__ cg,
                                        int b, int which,
                                        float* __restrict__ newxyz, float* __restrict__ out0,
                                        float* __restrict__ out2){
  #pragma clang fp contract(off)
  int t = threadIdx.x;
  __shared__ u64 slots[2][8];
  if (t < 16) ((u64*)slots)[t] = 0ull;
  v2 px[NV], py[NV], pz[NV], mind[NV];
  #pragma unroll
  for (int r = 0; r < NV; r++){
    int p0 = 1024*r + t, p1 = 1024*r + 512 + t;
    px[r].x = cx[p0]; px[r].y = cx[p1];
    py[r].x = cy[p0]; py[r].y = cy[p1];
    pz[r].x = cz[p0]; pz[r].y = cz[p1];
    mind[r].x = 1e10f; mind[r].y = 1e10f;
  }
  __syncthreads();
  float bv = 1e10f; int bi = t;   // all equal -> lowest local index
  for (int it = 0; it < 512; it++){
    u64 key = ((u64)(it+1) << 46) | ((u64)keyOf(bv) << 14) | (u64)(16383 - bi);
    atomicMax((unsigned long long*)&slots[it & 1][t & 7], (unsigned long long)key);
    __syncthreads();
    u64 k0 = slots[it & 1][0];
    #pragma unroll
    for (int i = 1; i < 8; i++){ u64 ki = slots[it & 1][i]; if (ki > k0) k0 = ki; }
    int sel = 16383 - (int)(k0 & 0x3FFFu);
    float xs = cx[sel], ys = cy[sel], zs = cz[sel];   // uniform L2-resident load
    if (t == 0){
      int s = which*512 + it;
      out2[b*1024 + s] = (float)cg[sel];
      newxyz[(b*1024 + s)*3]   = xs;
      newxyz[(b*1024 + s)*3+1] = ys;
      newxyz[(b*1024 + s)*3+2] = zs;
      out0[(b*1024 + s)*3]   = xs;
      out0[(b*1024 + s)*3+1] = ys;
      out0[(b*1024 + s)*3+2] = zs;
    }
    v2 xs2; xs2.x = xs; xs2.y = xs;
    v2 ys2; ys2.x = ys; ys2.y = ys;
    v2 zs2; zs2.x = zs; zs2.y = zs;
    bv = -1.0f; bi = 16383;
    #pragma unroll
    for (int r = 0; r < NV; r++){
      v2 dx = px[r] - xs2;
      v2 dy = py[r] - ys2;
      v2 dz = pz[r] - zs2;
      v2 qx = dx * dx;
      v2 qy = dy * dy;
      v2 qz = dz * dz;
      v2 s1 = qx + qy;
      v2 d  = s1 + qz;
      float m0 = fminf(mind[r].x, d.x);
      float m1 = fminf(mind[r].y, d.y);
      mind[r].x = m0; mind[r].y = m1;
      if (m0 > bv){ bv = m0; bi = 1024*r + t; }
      if (m1 > bv){ bv = m1; bi = 1024*r + 512 + t; }
    }
  }
}

__global__ __launch_bounds__(512) void k_fps(const float* __restrict__ cx, const float* __restrict__ cy,
                                             const float* __restrict__ cz, const int* __restrict__ cg,
                                             float* __restrict__ newxyz, float* __restrict__ out0,
                                             float* __restrict__ out2){
  int b = blockIdx.x >> 1; int which = blockIdx.x & 1;
  int base = b*16384 + (which ? 2048 : 0);
  if (which) fps_run<14>(cx+base, cy+base, cz+base, cg+base, b, 1, newxyz, out0, out2);
  else       fps_run<2 >(cx+base, cy+base, cz+base, cg+base, b, 0, newxyz, out0, out2);
}

// ---------- ball query: one wave per query (inclusive <=, f32 radius^2) ----------
__global__ __launch_bounds__(256) void k_ball(const float* __restrict__ xyz, const float* __restrict__ newxyz,
                                              int* __restrict__ idxnb){
  int t = threadIdx.x; int lane = t & 63;
  int qid = blockIdx.x*4 + (t >> 6);
  int b = qid >> 10;
  const float* xb = xyz + (size_t)b * NPT * 3;
  float qx = newxyz[qid*3], qy = newxyz[qid*3+1], qz = newxyz[qid*3+2];
  int found = 0, first = -1;
  for (int base = 0; base < NPT; base += 64){
    int p = base + lane;
    float x = xb[p*3], y = xb[p*3+1], z = xb[p*3+2];
    float dx = __fsub_rn(qx, x), dy = __fsub_rn(qy, y), dz = __fsub_rn(qz, z);
    float d2 = __fadd_rn(__fadd_rn(__fmul_rn(dx,dx), __fmul_rn(dy,dy)), __fmul_rn(dz,dz));
    bool w = d2 <= 0.09f;
    u64 m = __ballot(w);
    if (first < 0 && m) first = base + __ffsll((unsigned long long)m) - 1;
    if (w){
      int pos = found + __popcll(m & ((1ull << lane) - 1ull));
      if (pos < NS) idxnb[(size_t)qid*NS + pos] = p;
    }
    found += __popcll(m);
    if (found >= NS) break;
  }
  if (first < 0) first = 0;
  if (lane < NS && lane >= found) idxnb[(size_t)qid*NS + lane] = first;
}

// ---------- build grouped input Xb2 [kg][P][8] bf16 from transposed featT2 rows ----------
__global__ __launch_bounds__(256) void k_buildX(const float* __restrict__ xyz, const float* __restrict__ newxyz,
                                                const int* __restrict__ idxnb, const u16* __restrict__ featT2,
                                                u16* __restrict__ Xb2){
  int pos = blockIdx.x*256 + threadIdx.x;
  int b = pos >> 15; int r = pos & 32767; int s = r >> 5;
  int gi = idxnb[pos] & (NPT - 1);
  const float* xp = xyz + ((size_t)b*NPT + gi) * 3;
  const float* qp = newxyz + ((size_t)(b << 10) + s) * 3;
  u16 d0 = f2bf(__fsub_rn(xp[0], qp[0]));
  u16 d1 = f2bf(__fsub_rn(xp[1], qp[1]));
  u16 d2 = f2bf(__fsub_rn(xp[2], qp[2]));
  const uint4* row = (const uint4*)(featT2 + (size_t)(b*NPT + gi) * 160);
  #pragma unroll
  for (int kg = 0; kg < 20; kg++){
    uint4 u = row[kg];
    if (kg == 0){
      u.x = (u32)d0 | ((u32)d1 << 16);
      u.y = (u.y & 0xFFFF0000u) | (u32)d2;
    }
    *(uint4*)(Xb2 + ((size_t)kg*PP + pos)*8) = u;
  }
}

// ---------- MFMA conv layer: MT m-tiles/block (grid.y=1, B read once) ----------
// Optional fused BN-affine+relu on B load (unpack->fma->relu->RNE repack: bit-identical
// to the old k_affine pass). K8-packed bf16 out + f64 stat partials of RAW output.
template<int NKS, int MT, int AFF, int STORE>
__global__ __launch_bounds__(256) void k_mfma(const u16* __restrict__ Wb, int Kpad,
                                              const u16* __restrict__ Xp, const float2* __restrict__ aff,
                                              u16* __restrict__ Yp, double* __restrict__ cpart){
  __shared__ float sred[MT][4][16][16][2];
  int t = threadIdx.x;
  int w = t >> 6, lane = t & 63;
  int q = lane >> 4, c = lane & 15;
  int p0 = blockIdx.x * 64;
  f32x4 acc[MT][4];
  #pragma unroll
  for (int mt = 0; mt < MT; mt++)
    #pragma unroll
    for (int pp = 0; pp < 4; pp++) acc[mt][pp] = (f32x4){0.f,0.f,0.f,0.f};
  #pragma unroll
  for (int ks = 0; ks < NKS; ks++){
    float2 af[8];
    if (AFF){
      #pragma unroll
      for (int j = 0; j < 8; j++) af[j] = aff[(ks*4 + q)*8 + j];
    }
    bf16x8 afrag[MT];
    #pragma unroll
    for (int mt = 0; mt < MT; mt++){
      int m_w = (mt*4 + w)*16;
      afrag[mt] = *(const bf16x8*)(Wb + (size_t)(m_w + c)*Kpad + ks*32 + q*8);
    }
    #pragma unroll
    for (int pp = 0; pp < 4; pp++){
      int p = p0 + pp*16 + c;
      bf16x8 bfrag = *(const bf16x8*)(Xp + (((size_t)(ks*4 + q) * PP) + p) * 8);
      if (AFF){
        u32* bu = (u32*)&bfrag;
        #pragma unroll
        for (int i = 0; i < 4; i++){
          float v0 = fmaxf(0.f, fmaf(bf2f(bu[i] & 0xFFFFu), af[2*i].x,   af[2*i].y));
          float v1 = fmaxf(0.f, fmaf(bf2f(bu[i] >> 16),     af[2*i+1].x, af[2*i+1].y));
          bu[i] = (u32)f2bf(v0) | ((u32)f2bf(v1) << 16);
        }
      }
      #pragma unroll
      for (int mt = 0; mt < MT; mt++)
        acc[mt][pp] = __builtin_amdgcn_mfma_f32_16x16x32_bf16(afrag[mt], bfrag, acc[mt][pp], 0, 0, 0);
    }
  }
  #pragma unroll
  for (int mt = 0; mt < MT; mt++){
    #pragma unroll
    for (int reg = 0; reg < 4; reg++){
      float s = 0.f, sq = 0.f;
      #pragma unroll
      for (int pp = 0; pp < 4; pp++){ float v = acc[mt][pp][reg]; s += v; sq += v*v; }
      sred[mt][w][q*4+reg][c][0] = s; sred[mt][w][q*4+reg][c][1] = sq;
    }
    if (STORE){
      int m_w = (mt*4 + w)*16;
      int kgm = (m_w + q*4) >> 3;
      int j0 = (m_w + q*4) & 7;
      #pragma unroll
      for (int pp = 0; pp < 4; pp++){
        int p = p0 + pp*16 + c;
        ushort4 pk;
        pk.x = f2bf(acc[mt][pp][0]); pk.y = f2bf(acc[mt][pp][1]);
        pk.z = f2bf(acc[mt][pp][2]); pk.w = f2bf(acc[mt][pp][3]);
        *(ushort4*)(Yp + (((size_t)kgm * PP) + p) * 8 + j0) = pk;
      }
    }
  }
  __syncthreads();
  if (t < 64){
    int ww = t >> 4, ml = t & 15;
    #pragma unroll
    for (int mt = 0; mt < MT; mt++){
      double s = 0.0, qq = 0.0;
      for (int cc = 0; cc < 16; cc++){ s += sred[mt][ww][ml][cc][0]; qq += sred[mt][ww][ml][cc][1]; }
      int ch = (mt*4 + ww)*16 + ml;
      cpart[((size_t)ch * 2048 + blockIdx.x)*2] = s;
      cpart[((size_t)ch * 2048 + blockIdx.x)*2 + 1] = qq;
    }
  }
}

// ---------- layer-3 recompute via MFMA (MT=4, affined-on-load Y2) + BN3 + relu + maxpool epilogue ----------
__global__ __launch_bounds__(256) void k_mfma_pool(const u16* __restrict__ Wb,       // w3b [256][128]
                                                   const u16* __restrict__ Xp,       // RAW Y2 (K8)
                                                   const float2* __restrict__ aff1,  // ss1 (layer-2 affine)
                                                   const float2* __restrict__ ss2,
                                                   float* __restrict__ out1){
  int t = threadIdx.x;
  int w = t >> 6, lane = t & 63;
  int q = lane >> 4, c = lane & 15;
  int p0 = blockIdx.x * 64;
  f32x4 acc[4][4];
  #pragma unroll
  for (int mt = 0; mt < 4; mt++)
    #pragma unroll
    for (int pp = 0; pp < 4; pp++) acc[mt][pp] = (f32x4){0.f,0.f,0.f,0.f};
  #pragma unroll
  for (int ks = 0; ks < 4; ks++){
    float2 af[8];
    #pragma unroll
    for (int j = 0; j < 8; j++) af[j] = aff1[(ks*4 + q)*8 + j];
    bf16x8 afrag[4];
    #pragma unroll
    for (int mt = 0; mt < 4; mt++){
      int m_w = (mt*4 + w)*16;
      afrag[mt] = *(const bf16x8*)(Wb + (size_t)(m_w + c)*128 + ks*32 + q*8);
    }
    #pragma unroll
    for (int pp = 0; pp < 4; pp++){
      int p = p0 + pp*16 + c;
      bf16x8 bfrag = *(const bf16x8*)(Xp + (((size_t)(ks*4 + q) * PP) + p) * 8);
      u32* bu = (u32*)&bfrag;
      #pragma unroll
      for (int i = 0; i < 4; i++){
        float v0 = fmaxf(0.f, fmaf(bf2f(bu[i] & 0xFFFFu), af[2*i].x,   af[2*i].y));
        float v1 = fmaxf(0.f, fmaf(bf2f(bu[i] >> 16),     af[2*i+1].x, af[2*i+1].y));
        bu[i] = (u32)f2bf(v0) | ((u32)f2bf(v1) << 16);
      }
      #pragma unroll
      for (int mt = 0; mt < 4; mt++)
        acc[mt][pp] = __builtin_amdgcn_mfma_f32_16x16x32_bf16(afrag[mt], bfrag, acc[mt][pp], 0, 0, 0);
    }
  }
  int qid0 = blockIdx.x*2;
  #pragma unroll
  for (int mt = 0; mt < 4; mt++){
    int m_w = (mt*4 + w)*16;
    #pragma unroll
    for (int reg = 0; reg < 4; reg++){
      int m = m_w + q*4 + reg;
      float2 af = ss2[m];
      float x0 = fmaxf(0.f, fmaf(acc[mt][0][reg], af.x, af.y));
      float x1 = fmaxf(0.f, fmaf(acc[mt][1][reg], af.x, af.y));
      float x2 = fmaxf(0.f, fmaf(acc[mt][2][reg], af.x, af.y));
      float x3 = fmaxf(0.f, fmaf(acc[mt][3][reg], af.x, af.y));
      float v0 = row_max16(fmaxf(x0, x1));   // query qid0   (p 0..31 of block)
      float v1 = row_max16(fmaxf(x2, x3));   // query qid0+1 (p 32..63)
      if (c == 15){
        int qa = qid0, qb = qid0 + 1;
        out1[((size_t)(qa >> 10) << 18) + (size_t)m*1024 + (qa & 1023)] = v0;
        out1[((size_t)(qb >> 10) << 18) + (size_t)m*1024 + (qb & 1023)] = v1;
      }
    }
  }
}

__global__ __launch_bounds__(256) void k_stats_conv(const double* __restrict__ cpart,
                                                    const float* __restrict__ g, const float* __restrict__ bt,
                                                    float2* __restrict__ ssv){
  __shared__ double rs_[256], rq_[256];
  int ch = blockIdx.x, t = threadIdx.x;
  double s = 0.0, q = 0.0;
  for (int i = t; i < 2048; i += 256){ s += cpart[((size_t)ch*2048 + i)*2]; q += cpart[((size_t)ch*2048 + i)*2+1]; }
  rs_[t] = s; rq_[t] = q; __syncthreads();
  for (int off = 128; off; off >>= 1){
    if (t < off){ rs_[t] += rs_[t+off]; rq_[t] += rq_[t+off]; }
    __syncthreads();
  }
  if (t == 0){
    double cnt = (double)PP;
    double mu = rs_[0]/cnt; double var = rq_[0]/cnt - mu*mu;
    float rsf = 1.0f / sqrtf((float)var + 1e-5f);
    double rsd = (double)rsf;
    double gd = (double)g[ch]; double bd = (double)bt[ch];
    ssv[ch] = make_float2((float)(rsd*gd), (float)(bd - mu*rsd*gd));
  }
}

extern "C" void kernel_launch(void* const* d_in, const int* in_sizes, int n_in,
                              void* d_out, int out_size, void* d_ws, size_t ws_size,
                              hipStream_t stream){
  (void)in_sizes; (void)n_in; (void)out_size;
  if (ws_size < WS_NEED) return;
  const float* xyz    = (const float*)d_in[0];
  const float* feat   = (const float*)d_in[1];
  const float* w1     = (const float*)d_in[2];
  const float* g1     = (const float*)d_in[3];
  const float* b1     = (const float*)d_in[4];
  const float* w2     = (const float*)d_in[5];
  const float* g2     = (const float*)d_in[6];
  const float* b2     = (const float*)d_in[7];
  const float* w3     = (const float*)d_in[8];
  const float* g3     = (const float*)d_in[9];
  const float* b3     = (const float*)d_in[10];
  const float* fw1    = (const float*)d_in[11];
  const float* fg1    = (const float*)d_in[12];
  const float* fb1    = (const float*)d_in[13];
  const float* fw2    = (const float*)d_in[14];
  const float* fbias2 = (const float*)d_in[15];

  char* ws = (char*)d_ws;
  float*  newxyz = (float*)(ws + OFF_NEWXYZ);
  float*  margin = (float*)(ws + OFF_MARGIN);
  u32*    fgmask = (u32*)(ws + OFF_FGMASK);
  int*    idxnb  = (int*)(ws + OFF_IDXNB);
  float*  mstat  = (float*)(ws + OFF_MSTAT);
  float2* ss0    = (float2*)(ws + OFF_SSA);
  float2* ss1    = ss0 + 128;
  float2* ss2    = ss0 + 256;
  float*  wt0    = (float*)(ws + OFF_WT0);
  u16*    w1b    = (u16*)(ws + OFF_W1B);
  u16*    w2b    = (u16*)(ws + OFF_W2B);
  u16*    w3b    = (u16*)(ws + OFF_W3B);
  double* mpart  = (double*)(ws + OFF_MPART);
  double* cpart  = (double*)(ws + OFF_CPART);
  // Region B phases: featT2 (21MB, dead after k_buildX) -> Y1p (32MB K8)
  u16*    featT2 = (u16*)(ws + OFF_REGB);
  u16*    Y1p    = (u16*)(ws + OFF_REGB);
  // Region A phases: y0 (16MB f32) -> cx/cy/cz/cg (1MB) -> Xb2 (40MB K8) -> Y2p (32MB K8)
  float*  y0     = (float*)(ws + OFF_REGA);
  float*  cx     = (float*)(ws + OFF_REGA);
  float*  cy     = cx + 4*16384;
  float*  cz     = cy + 4*16384;
  int*    cg     = (int*)(cz + 4*16384);
  u16*    Xb2    = (u16*)(ws + OFF_REGA);
  u16*    Y2p    = (u16*)(ws + OFF_REGA);

  float* out  = (float*)d_out;
  float* out0 = out;            // [4,1024,3]
  float* out1 = out + 12288;    // [4,256,1024]
  float* out2 = out + 1060864;  // [4,1024]
  float* out3 = out + 1064960;  // [4,2,16384]

  k_prep<<<dim3(256), dim3(256), 0, stream>>>(w1, w2, w3, fw1, wt0, w1b, w2b, w3b);
  k_prepT<<<dim3(256,4), dim3(256), 0, stream>>>(feat, featT2);
  k_gemm_mask<<<dim3(256,1,4), dim3(256), 0, stream>>>(wt0, feat, y0, mpart);
  k_mask_stats<<<dim3(1), dim3(64), 0, stream>>>(mpart, mstat);
  k_scores<<<dim3(64,4), dim3(256), 0, stream>>>(y0, mstat, fg1, fb1, fw2, fbias2, margin, out3);
  k_topk<<<dim3(4), dim3(1024), 0, stream>>>(margin, fgmask);
  k_compact<<<dim3(8), dim3(1024), 0, stream>>>(xyz, fgmask, cx, cy, cz, cg);
  k_fps<<<dim3(8), dim3(512), 0, stream>>>(cx, cy, cz, cg, newxyz, out0, out2);
  k_ball<<<dim3(1024), dim3(256), 0, stream>>>(xyz, newxyz, idxnb);
  k_buildX<<<dim3(512), dim3(256), 0, stream>>>(xyz, newxyz, idxnb, featT2, Xb2);
  k_mfma<5,2,0,1><<<dim3(2048), dim3(256), 0, stream>>>(w1b, 160, Xb2, nullptr, Y1p, cpart);
  k_stats_conv<<<dim3(128), dim3(256), 0, stream>>>(cpart, g1, b1, ss0);
  k_mfma<4,2,1,1><<<dim3(2048), dim3(256), 0, stream>>>(w2b, 128, Y1p, ss0, Y2p, cpart);
  k_stats_conv<<<dim3(128), dim3(256), 0, stream>>>(cpart, g2, b2, ss1);
  k_mfma<4,4,1,0><<<dim3(2048), dim3(256), 0, stream>>>(w3b, 128, Y2p, ss1, (u16*)nullptr, cpart);
  k_stats_conv<<<dim3(256), dim3(256), 0, stream>>>(cpart, g3, b3, ss2);
  k_mfma_pool<<<dim3(2048), dim3(256), 0, stream>>>(w3b, Y2p, ss1, ss2, out1);
}